// Round 3
// baseline (9346.570 us; speedup 1.0000x reference)
//
#include <hip/hip_runtime.h>
#include <hip/hip_bf16.h>

#define NN 500000
#define NE 8000000
#define STR 12          // padded node-feature stride (10 used + 2 pad) -> 48B, 16B-aligned
#define BN_EPS 1e-5f

__device__ __forceinline__ float waveReduce(float v) {
#pragma unroll
    for (int o = 32; o > 0; o >>= 1) v += __shfl_down(v, o, 64);
    return v;
}

// ---------------- edge pass 1: agg1[dst]+=x[src]; deg[src]+=w; two_m=sum(w) ----
__global__ __launch_bounds__(256) void edge_pass1(
    const int* __restrict__ src, const int* __restrict__ dst,
    const float* __restrict__ w, const float* __restrict__ x,
    float* __restrict__ agg1, float* __restrict__ deg, float* __restrict__ two_m)
{
    float wsum = 0.f;
    int stride = gridDim.x * blockDim.x;
    for (int e = blockIdx.x * blockDim.x + threadIdx.x; e < NE; e += stride) {
        int s0 = src[e], d0 = dst[e];
        float we = w[e];
        atomicAdd(&agg1[d0], x[s0]);
        atomicAdd(&deg[s0], we);
        wsum += we;
    }
    __shared__ float red[4];
    float v = waveReduce(wsum);
    int lane = threadIdx.x & 63, wid = threadIdx.x >> 6;
    if (lane == 0) red[wid] = v;
    __syncthreads();
    if (threadIdx.x == 0) atomicAdd(two_m, red[0] + red[1] + red[2] + red[3]);
}

// ---------------- node pass 1: h = MLP(x + agg1), stats ------------------------
__global__ __launch_bounds__(256) void node_pass1(
    const float* __restrict__ x, const float* __restrict__ agg1,
    const float* __restrict__ Wa, const float* __restrict__ ba,
    const float* __restrict__ Wb, const float* __restrict__ bb,
    float* __restrict__ hout, float* __restrict__ sum_ptr, float* __restrict__ sq_ptr)
{
    __shared__ float sWa[10], sba[10], sWb[100], sbb[10];
    int tid = threadIdx.x;
    if (tid < 100) sWb[tid] = Wb[tid];
    if (tid < 10) { sWa[tid] = Wa[tid]; sba[tid] = ba[tid]; sbb[tid] = bb[tid]; }
    __syncthreads();

    int i = blockIdx.x * blockDim.x + tid;
    float h[10];
    if (i < NN) {
        float h0 = x[i] + agg1[i];
        float t[10];
#pragma unroll
        for (int j = 0; j < 10; j++) t[j] = h0 * sWa[j] + sba[j];
#pragma unroll
        for (int j = 0; j < 10; j++) h[j] = sbb[j];
#pragma unroll
        for (int k = 0; k < 10; k++) {
            float tv = t[k];
#pragma unroll
            for (int j = 0; j < 10; j++) h[j] += tv * sWb[k * 10 + j];
        }
        float* ho = hout + (size_t)i * STR;
#pragma unroll
        for (int j = 0; j < 10; j++) ho[j] = h[j];
    } else {
#pragma unroll
        for (int j = 0; j < 10; j++) h[j] = 0.f;
    }

    __shared__ float part[4][20];
    int lane = tid & 63, wid = tid >> 6;
#pragma unroll
    for (int j = 0; j < 10; j++) {
        float sv = waveReduce(h[j]);
        float qv = waveReduce(h[j] * h[j]);
        if (lane == 0) { part[wid][j] = sv; part[wid][10 + j] = qv; }
    }
    __syncthreads();
    if (tid < 20) {
        float v = part[0][tid] + part[1][tid] + part[2][tid] + part[3][tid];
        if (tid < 10) atomicAdd(sum_ptr + tid, v);
        else          atomicAdd(sq_ptr + tid - 10, v);
    }
}

// ---------------- BN finalize: scale/shift -------------------------------------
__global__ void bn_fin(const float* __restrict__ sum_ptr, const float* __restrict__ sq_ptr,
                       const float* __restrict__ g, const float* __restrict__ be,
                       float* __restrict__ scale_out, float* __restrict__ shift_out)
{
    int j = threadIdx.x;
    if (j < 10) {
        const float invN = 1.f / (float)NN;
        float mu = sum_ptr[j] * invN;
        float var = sq_ptr[j] * invN - mu * mu;
        float rs = rsqrtf(var + BN_EPS);
        float sc = g[j] * rs;
        scale_out[j] = sc;
        shift_out[j] = be[j] - mu * sc;
    }
}

// ---------------- edge pass (layers 2/3): agg[dst] += affine(hprev[src]) -------
__global__ __launch_bounds__(256) void edge_pass23(
    const int* __restrict__ src, const int* __restrict__ dst,
    const float* __restrict__ hprev,
    const float* __restrict__ scale, const float* __restrict__ shift,
    float* __restrict__ agg)
{
    __shared__ float ssc[10], ssh[10];
    if (threadIdx.x < 10) { ssc[threadIdx.x] = scale[threadIdx.x]; ssh[threadIdx.x] = shift[threadIdx.x]; }
    __syncthreads();
    float sc[10], sh[10];
#pragma unroll
    for (int j = 0; j < 10; j++) { sc[j] = ssc[j]; sh[j] = ssh[j]; }

    int stride = gridDim.x * blockDim.x;
    for (int e = blockIdx.x * blockDim.x + threadIdx.x; e < NE; e += stride) {
        int s0 = src[e], d0 = dst[e];
        const float4* hp = reinterpret_cast<const float4*>(hprev + (size_t)s0 * STR);
        float4 a = hp[0], b = hp[1], c = hp[2];   // c.z/c.w are pad, unused
        float v[10] = {a.x, a.y, a.z, a.w, b.x, b.y, b.z, b.w, c.x, c.y};
        float* ad = agg + (size_t)d0 * STR;
#pragma unroll
        for (int j = 0; j < 10; j++) atomicAdd(ad + j, v[j] * sc[j] + sh[j]);
    }
}

// ---------------- node pass (layers 2/3) ---------------------------------------
__global__ __launch_bounds__(256) void node_pass23(
    const float* __restrict__ hprev, const float* __restrict__ agg,
    const float* __restrict__ scp, const float* __restrict__ shp,
    const float* __restrict__ Wa, const float* __restrict__ ba,
    const float* __restrict__ Wb, const float* __restrict__ bb,
    float* __restrict__ hout, float* __restrict__ sum_ptr, float* __restrict__ sq_ptr)
{
    __shared__ float sWa[100], sWb[100], sba[10], sbb[10], sscp[10], sshp[10];
    int tid = threadIdx.x;
    if (tid < 100) { sWa[tid] = Wa[tid]; sWb[tid] = Wb[tid]; }
    if (tid < 10) {
        sba[tid] = ba[tid]; sbb[tid] = bb[tid];
        sscp[tid] = scp[tid]; sshp[tid] = shp[tid];
    }
    __syncthreads();

    int i = blockIdx.x * blockDim.x + tid;
    float h[10];
    if (i < NN) {
        const float* hp = hprev + (size_t)i * STR;
        const float* ag = agg + (size_t)i * STR;
        float h0[10], t[10];
#pragma unroll
        for (int j = 0; j < 10; j++) h0[j] = hp[j] * sscp[j] + sshp[j] + ag[j];
#pragma unroll
        for (int j = 0; j < 10; j++) t[j] = sba[j];
#pragma unroll
        for (int k = 0; k < 10; k++) {
            float hv = h0[k];
#pragma unroll
            for (int j = 0; j < 10; j++) t[j] += hv * sWa[k * 10 + j];
        }
#pragma unroll
        for (int j = 0; j < 10; j++) h[j] = sbb[j];
#pragma unroll
        for (int k = 0; k < 10; k++) {
            float tv = t[k];
#pragma unroll
            for (int j = 0; j < 10; j++) h[j] += tv * sWb[k * 10 + j];
        }
        float* ho = hout + (size_t)i * STR;
#pragma unroll
        for (int j = 0; j < 10; j++) ho[j] = h[j];
    } else {
#pragma unroll
        for (int j = 0; j < 10; j++) h[j] = 0.f;
    }

    __shared__ float part[4][20];
    int lane = tid & 63, wid = tid >> 6;
#pragma unroll
    for (int j = 0; j < 10; j++) {
        float sv = waveReduce(h[j]);
        float qv = waveReduce(h[j] * h[j]);
        if (lane == 0) { part[wid][j] = sv; part[wid][10 + j] = qv; }
    }
    __syncthreads();
    if (tid < 20) {
        float v = part[0][tid] + part[1][tid] + part[2][tid] + part[3][tid];
        if (tid < 10) atomicAdd(sum_ptr + tid, v);
        else          atomicAdd(sq_ptr + tid - 10, v);
    }
}

// ---------------- final node pass: concat-affine -> logits -> softmax -> s, ds --
__global__ __launch_bounds__(256) void final_node(
    const float* __restrict__ h1, const float* __restrict__ h2, const float* __restrict__ h3,
    const float* __restrict__ scl, const float* __restrict__ shf,   // 30 each
    const float* __restrict__ Wf, const float* __restrict__ bfb,
    const float* __restrict__ deg, float* __restrict__ sout, float* __restrict__ ds_acc)
{
    __shared__ float sW[120], sb[4], ssc[30], ssh[30];
    int tid = threadIdx.x;
    if (tid < 120) sW[tid] = Wf[tid];
    if (tid < 4) sb[tid] = bfb[tid];
    if (tid < 30) { ssc[tid] = scl[tid]; ssh[tid] = shf[tid]; }
    __syncthreads();

    int i = blockIdx.x * blockDim.x + tid;
    float sv[4] = {0.f, 0.f, 0.f, 0.f};
    if (i < NN) {
        float xc[30];
        const float* p1 = h1 + (size_t)i * STR;
        const float* p2 = h2 + (size_t)i * STR;
        const float* p3 = h3 + (size_t)i * STR;
#pragma unroll
        for (int j = 0; j < 10; j++) {
            xc[j]      = p1[j] * ssc[j]      + ssh[j];
            xc[10 + j] = p2[j] * ssc[10 + j] + ssh[10 + j];
            xc[20 + j] = p3[j] * ssc[20 + j] + ssh[20 + j];
        }
        float lg[4];
#pragma unroll
        for (int k = 0; k < 4; k++) lg[k] = sb[k];
#pragma unroll
        for (int m = 0; m < 30; m++) {
            float xv = xc[m];
#pragma unroll
            for (int k = 0; k < 4; k++) lg[k] += xv * sW[m * 4 + k];
        }
        float mx = fmaxf(fmaxf(lg[0], lg[1]), fmaxf(lg[2], lg[3]));
        float e0 = __expf(lg[0] - mx), e1 = __expf(lg[1] - mx);
        float e2 = __expf(lg[2] - mx), e3 = __expf(lg[3] - mx);
        float inv = 1.f / (e0 + e1 + e2 + e3);
        float s0 = e0 * inv, s1 = e1 * inv, s2 = e2 * inv, s3 = e3 * inv;
        float4 pk; pk.x = s0; pk.y = s1; pk.z = s2; pk.w = s3;
        reinterpret_cast<float4*>(sout)[i] = pk;
        float dg = deg[i];
        sv[0] = dg * s0; sv[1] = dg * s1; sv[2] = dg * s2; sv[3] = dg * s3;
    }
    __shared__ float part[4][4];
    int lane = tid & 63, wid = tid >> 6;
#pragma unroll
    for (int k = 0; k < 4; k++) {
        float r = waveReduce(sv[k]);
        if (lane == 0) part[wid][k] = r;
    }
    __syncthreads();
    if (tid < 4) atomicAdd(ds_acc + tid, part[0][tid] + part[1][tid] + part[2][tid] + part[3][tid]);
}

// ---------------- modularity edge pass: pos = sum w * <s_src, s_dst> -----------
__global__ __launch_bounds__(256) void mod_edge(
    const int* __restrict__ src, const int* __restrict__ dst,
    const float* __restrict__ w, const float* __restrict__ s, float* __restrict__ pos)
{
    const float4* s4 = reinterpret_cast<const float4*>(s);
    float acc = 0.f;
    int stride = gridDim.x * blockDim.x;
    for (int e = blockIdx.x * blockDim.x + threadIdx.x; e < NE; e += stride) {
        float4 ua = s4[src[e]];
        float4 ub = s4[dst[e]];
        float dot = ua.x * ub.x + ua.y * ub.y + ua.z * ub.z + ua.w * ub.w;
        acc += w[e] * dot;
    }
    __shared__ float red[4];
    float v = waveReduce(acc);
    int lane = threadIdx.x & 63, wid = threadIdx.x >> 6;
    if (lane == 0) red[wid] = v;
    __syncthreads();
    if (threadIdx.x == 0) atomicAdd(pos, red[0] + red[1] + red[2] + red[3]);
}

// ---------------- q ------------------------------------------------------------
__global__ void q_kernel(const float* __restrict__ sc, float* __restrict__ out)
{
    if (threadIdx.x == 0) {
        float inv = 1.f / sc[128];
        float posv = sc[129] * inv;
        float acc = 0.f;
#pragma unroll
        for (int k = 0; k < 4; k++) {
            float d = sc[132 + k] * inv;
            acc += d * d;
        }
        out[(size_t)NN * 4] = posv - acc;
    }
}

extern "C" void kernel_launch(void* const* d_in, const int* in_sizes, int n_in,
                              void* d_out, int out_size, void* d_ws, size_t ws_size,
                              hipStream_t stream) {
    const float* x  = (const float*)d_in[0];
    const int*  ei  = (const int*)d_in[1];
    const int*  src = ei;
    const int*  dst = ei + NE;
    const float* w   = (const float*)d_in[2];
    const float* W1a = (const float*)d_in[3];  const float* b1a = (const float*)d_in[4];
    const float* W1b = (const float*)d_in[5];  const float* b1b = (const float*)d_in[6];
    const float* g1  = (const float*)d_in[7];  const float* be1 = (const float*)d_in[8];
    const float* W2a = (const float*)d_in[9];  const float* b2a = (const float*)d_in[10];
    const float* W2b = (const float*)d_in[11]; const float* b2b = (const float*)d_in[12];
    const float* g2  = (const float*)d_in[13]; const float* be2 = (const float*)d_in[14];
    const float* W3a = (const float*)d_in[15]; const float* b3a = (const float*)d_in[16];
    const float* W3b = (const float*)d_in[17]; const float* b3b = (const float*)d_in[18];
    const float* g3  = (const float*)d_in[19]; const float* be3 = (const float*)d_in[20];
    const float* Wf  = (const float*)d_in[21]; const float* bfb = (const float*)d_in[22];

    // workspace layout (floats):
    //  [0..255]   scalars: sums 3x10 @0, sqs 3x10 @30, scale 3x10 @64, shift 3x10 @96,
    //             two_m @128, pos @129, ds[4] @132
    //  [256..)    deg[NN]
    //  then agg[12*NN], h1[12*NN], h2[12*NN], h3[12*NN]
    float* sc  = (float*)d_ws;
    float* deg = sc + 256;
    float* agg = deg + NN;
    float* h1  = agg + (size_t)12 * NN;
    float* h2  = h1 + (size_t)12 * NN;
    float* h3  = h2 + (size_t)12 * NN;
    float* sout = (float*)d_out;

    const int NB_NODE = (NN + 255) / 256;
    const int NB_EDGE = 8192;

    // zero scalars + deg + agg (contiguous)
    hipMemsetAsync(sc, 0, (size_t)(256 + NN + (size_t)12 * NN) * sizeof(float), stream);

    // layer 1 (agg used with stride 1)
    edge_pass1<<<NB_EDGE, 256, 0, stream>>>(src, dst, w, x, agg, deg, sc + 128);
    node_pass1<<<NB_NODE, 256, 0, stream>>>(x, agg, W1a, b1a, W1b, b1b, h1, sc + 0, sc + 30);
    bn_fin<<<1, 64, 0, stream>>>(sc + 0, sc + 30, g1, be1, sc + 64, sc + 96);

    // layer 2
    hipMemsetAsync(agg, 0, (size_t)12 * NN * sizeof(float), stream);
    edge_pass23<<<NB_EDGE, 256, 0, stream>>>(src, dst, h1, sc + 64, sc + 96, agg);
    node_pass23<<<NB_NODE, 256, 0, stream>>>(h1, agg, sc + 64, sc + 96, W2a, b2a, W2b, b2b,
                                             h2, sc + 10, sc + 40);
    bn_fin<<<1, 64, 0, stream>>>(sc + 10, sc + 40, g2, be2, sc + 74, sc + 106);

    // layer 3
    hipMemsetAsync(agg, 0, (size_t)12 * NN * sizeof(float), stream);
    edge_pass23<<<NB_EDGE, 256, 0, stream>>>(src, dst, h2, sc + 74, sc + 106, agg);
    node_pass23<<<NB_NODE, 256, 0, stream>>>(h2, agg, sc + 74, sc + 106, W3a, b3a, W3b, b3b,
                                             h3, sc + 20, sc + 50);
    bn_fin<<<1, 64, 0, stream>>>(sc + 20, sc + 50, g3, be3, sc + 84, sc + 116);

    // final: softmax s + ds partials, then modularity
    final_node<<<NB_NODE, 256, 0, stream>>>(h1, h2, h3, sc + 64, sc + 96, Wf, bfb,
                                            deg, sout, sc + 132);
    mod_edge<<<NB_EDGE, 256, 0, stream>>>(src, dst, w, sout, sc + 129);
    q_kernel<<<1, 64, 0, stream>>>(sc, sout);
}

// Round 4
// 2320.870 us; speedup vs baseline: 4.0272x; 4.0272x over previous
//
#include <hip/hip_runtime.h>

#define NN 500000
#define NE 8000000
#define NEQ (NE / 4)          // edges are processed 4 per thread, 8M % 4 == 0
#define BN_EPS 1e-5f

__device__ __forceinline__ float waveReduceF(float v) {
#pragma unroll
    for (int o = 32; o > 0; o >>= 1) v += __shfl_down(v, o, 64);
    return v;
}
__device__ __forceinline__ double waveReduceD(double v) {
#pragma unroll
    for (int o = 32; o > 0; o >>= 1) v += __shfl_down(v, o, 64);
    return v;
}

// ---------------- E1: U[dst] += x[src]; NC[dst] += 1 ---------------------------
__global__ __launch_bounds__(256) void edge1(
    const int* __restrict__ src, const int* __restrict__ dst,
    const float* __restrict__ x, float* __restrict__ U, float* __restrict__ NC)
{
    int t = blockIdx.x * 256 + threadIdx.x;
    if (t >= NEQ) return;
    int4 s4 = reinterpret_cast<const int4*>(src)[t];
    int4 d4 = reinterpret_cast<const int4*>(dst)[t];
    float x0 = x[s4.x], x1 = x[s4.y], x2 = x[s4.z], x3 = x[s4.w];
    atomicAdd(&U[d4.x], x0); atomicAdd(&U[d4.y], x1);
    atomicAdd(&U[d4.z], x2); atomicAdd(&U[d4.w], x3);
    atomicAdd(&NC[d4.x], 1.f); atomicAdd(&NC[d4.y], 1.f);
    atomicAdd(&NC[d4.z], 1.f); atomicAdd(&NC[d4.w], 1.f);
}

// ---------------- N1: u = x + agg(x); pack (u,n) -------------------------------
__global__ __launch_bounds__(256) void node1(
    const float* __restrict__ x, float* __restrict__ U,
    const float* __restrict__ NC, float2* __restrict__ UN2)
{
    int i = blockIdx.x * 256 + threadIdx.x;
    if (i >= NN) return;
    float u = x[i] + U[i];
    U[i] = u;
    UN2[i] = make_float2(u, NC[i]);
}

// ---------------- E2: SU[dst] += u[src]; SN[dst] += n[src] ---------------------
__global__ __launch_bounds__(256) void edge2(
    const int* __restrict__ src, const int* __restrict__ dst,
    const float2* __restrict__ UN2,
    float* __restrict__ SU, float* __restrict__ SN)
{
    int t = blockIdx.x * 256 + threadIdx.x;
    if (t >= NEQ) return;
    int4 s4 = reinterpret_cast<const int4*>(src)[t];
    int4 d4 = reinterpret_cast<const int4*>(dst)[t];
    float2 a0 = UN2[s4.x], a1 = UN2[s4.y], a2 = UN2[s4.z], a3 = UN2[s4.w];
    atomicAdd(&SU[d4.x], a0.x); atomicAdd(&SN[d4.x], a0.y);
    atomicAdd(&SU[d4.y], a1.x); atomicAdd(&SN[d4.y], a1.y);
    atomicAdd(&SU[d4.z], a2.x); atomicAdd(&SN[d4.z], a2.y);
    atomicAdd(&SU[d4.w], a3.x); atomicAdd(&SN[d4.w], a3.y);
}

// ---------------- E3: SSU[dst] += su[src] --------------------------------------
__global__ __launch_bounds__(256) void edge3(
    const int* __restrict__ src, const int* __restrict__ dst,
    const float* __restrict__ SU, float* __restrict__ SSU)
{
    int t = blockIdx.x * 256 + threadIdx.x;
    if (t >= NEQ) return;
    int4 s4 = reinterpret_cast<const int4*>(src)[t];
    int4 d4 = reinterpret_cast<const int4*>(dst)[t];
    float v0 = SU[s4.x], v1 = SU[s4.y], v2 = SU[s4.z], v3 = SU[s4.w];
    atomicAdd(&SSU[d4.x], v0); atomicAdd(&SSU[d4.y], v1);
    atomicAdd(&SSU[d4.z], v2); atomicAdd(&SSU[d4.w], v3);
}

// ---------------- M: first+second moments of (u,n,su,sn,ssu) in f64 ------------
__global__ __launch_bounds__(256) void moments(
    const float* __restrict__ U, const float* __restrict__ NC,
    const float* __restrict__ SU, const float* __restrict__ SN,
    const float* __restrict__ SSU, double* __restrict__ dm)
{
    int i = blockIdx.x * 256 + threadIdx.x;
    double z[5] = {0, 0, 0, 0, 0};
    if (i < NN) {
        z[0] = (double)U[i]; z[1] = (double)NC[i]; z[2] = (double)SU[i];
        z[3] = (double)SN[i]; z[4] = (double)SSU[i];
    }
    double m[20];
#pragma unroll
    for (int a = 0; a < 5; a++) m[a] = z[a];
    int idx = 5;
#pragma unroll
    for (int a = 0; a < 5; a++)
#pragma unroll
        for (int b = a; b < 5; b++) m[idx++] = z[a] * z[b];

    __shared__ double part[4][20];
    int lane = threadIdx.x & 63, wid = threadIdx.x >> 6;
#pragma unroll
    for (int k = 0; k < 20; k++) {
        double r = waveReduceD(m[k]);
        if (lane == 0) part[wid][k] = r;
    }
    __syncthreads();
    if (threadIdx.x < 20)
        atomicAdd(&dm[threadIdx.x],
                  part[0][threadIdx.x] + part[1][threadIdx.x] +
                  part[2][threadIdx.x] + part[3][threadIdx.x]);
}

// ---------------- K: fold weights + moments into the 4x6 logit matrix ----------
__device__ void mm1010(const float* in, const float* Wa, const float* Wb, float* out)
{
    float t[10];
    for (int m = 0; m < 10; m++) {
        float acc = 0.f;
        for (int k = 0; k < 10; k++) acc += in[k] * Wa[k * 10 + m];
        t[m] = acc;
    }
    for (int j = 0; j < 10; j++) {
        float acc = 0.f;
        for (int m = 0; m < 10; m++) acc += t[m] * Wb[m * 10 + j];
        out[j] = acc;
    }
}

__global__ void constk(
    const float* __restrict__ W1a, const float* __restrict__ b1a,
    const float* __restrict__ W1b, const float* __restrict__ b1b,
    const float* __restrict__ g1, const float* __restrict__ be1,
    const float* __restrict__ W2a, const float* __restrict__ b2a,
    const float* __restrict__ W2b, const float* __restrict__ b2b,
    const float* __restrict__ g2, const float* __restrict__ be2,
    const float* __restrict__ W3a, const float* __restrict__ b3a,
    const float* __restrict__ W3b, const float* __restrict__ b3b,
    const float* __restrict__ g3, const float* __restrict__ be3,
    const float* __restrict__ Wf, const float* __restrict__ bf_,
    const double* __restrict__ dm, float* __restrict__ Lout)
{
    if (threadIdx.x != 0 || blockIdx.x != 0) return;
    const double invN = 1.0 / (double)NN;
    double E[5];
    for (int m = 0; m < 5; m++) E[m] = dm[m] * invN;
    double C[5][5];
    {
        int idx = 5;
        for (int a = 0; a < 5; a++)
            for (int b = a; b < 5; b++) {
                double c = dm[idx++] * invN - E[a] * E[b];
                C[a][b] = c; C[b][a] = c;
            }
    }
    // ----- layer 1: h1 = u*v + c1 -----
    float v[10], c1[10];
    for (int j = 0; j < 10; j++) {
        float av = 0.f, ac = 0.f;
        for (int k = 0; k < 10; k++) {
            av += W1a[k] * W1b[k * 10 + j];
            ac += b1a[k] * W1b[k * 10 + j];
        }
        v[j] = av; c1[j] = ac + b1b[j];
    }
    double Eu = E[0], Vu = C[0][0];
    float p[10], q[10];
    for (int j = 0; j < 10; j++) {
        float var1 = (float)(Vu * (double)v[j] * (double)v[j]);
        float sc1 = g1[j] * rsqrtf(var1 + BN_EPS);
        p[j] = sc1 * v[j];
        q[j] = be1[j] - (float)Eu * p[j];
    }
    // ----- layer 2: h2 = a*r + b*s + d2 ; a=u+su, b=1+n -----
    float r[10], s[10], d2[10];
    mm1010(p, W2a, W2b, r);
    mm1010(q, W2a, W2b, s);
    for (int j = 0; j < 10; j++) {
        float acc = b2b[j];
        for (int m = 0; m < 10; m++) acc += b2a[m] * W2b[m * 10 + j];
        d2[j] = acc;
    }
    double Ea = E[0] + E[2], Eb = 1.0 + E[1];
    double Va = C[0][0] + 2.0 * C[0][2] + C[2][2];
    double Vb = C[1][1];
    double Cab = C[0][1] + C[2][1];
    float rt[10], st[10], dt[10];
    for (int j = 0; j < 10; j++) {
        double rj = r[j], sj = s[j];
        float var2 = (float)(Va * rj * rj + Vb * sj * sj + 2.0 * Cab * rj * sj);
        float sc2 = g2[j] * rsqrtf(var2 + BN_EPS);
        rt[j] = sc2 * r[j];
        st[j] = sc2 * s[j];
        dt[j] = be2[j] - sc2 * (float)(Ea * rj + Eb * sj);
    }
    // ----- layer 3: h3 = A*r3 + B*s3 + C*t3 + d3 ; A=u+2su+ssu, B=1+2n+sn, Cc=1+n
    float r3[10], s3[10], t3[10], d3[10];
    mm1010(rt, W3a, W3b, r3);
    mm1010(st, W3a, W3b, s3);
    mm1010(dt, W3a, W3b, t3);
    for (int j = 0; j < 10; j++) {
        float acc = b3b[j];
        for (int m = 0; m < 10; m++) acc += b3a[m] * W3b[m * 10 + j];
        d3[j] = acc;
    }
    const double gA[5] = {1, 0, 2, 0, 1};
    const double gB[5] = {0, 2, 0, 1, 0};
    const double gC[5] = {0, 1, 0, 0, 0};
    double EA = E[0] + 2.0 * E[2] + E[4];
    double EB = 1.0 + 2.0 * E[1] + E[3];
    double EC = 1.0 + E[1];
    double VA = 0, VB = 0, VC = 0, CAB = 0, CAC = 0, CBC = 0;
    for (int a = 0; a < 5; a++)
        for (int b = 0; b < 5; b++) {
            double c = C[a][b];
            VA  += gA[a] * gA[b] * c;
            VB  += gB[a] * gB[b] * c;
            VC  += gC[a] * gC[b] * c;
            CAB += gA[a] * gB[b] * c;
            CAC += gA[a] * gC[b] * c;
            CBC += gB[a] * gC[b] * c;
        }
    float rh[10], sh[10], th[10], dh[10];
    for (int j = 0; j < 10; j++) {
        double rj = r3[j], sj = s3[j], tj = t3[j];
        float var3 = (float)(VA * rj * rj + VB * sj * sj + VC * tj * tj
                             + 2.0 * (CAB * rj * sj + CAC * rj * tj + CBC * sj * tj));
        float sc3 = g3[j] * rsqrtf(var3 + BN_EPS);
        rh[j] = sc3 * r3[j];
        sh[j] = sc3 * s3[j];
        th[j] = sc3 * t3[j];
        dh[j] = be3[j] - sc3 * (float)(EA * rj + EB * sj + EC * tj);
    }
    // ----- logits = Lu*u + Ln*n + Lsu*su + Lsn*sn + Lssu*ssu + L0 -----
    // x11 = u p + q
    // x12 = u rt + su rt + n st + (st + dt)
    // x13 = u rh + su(2rh) + ssu rh + n(2sh+th) + sn sh + (sh + th + dh)
    for (int k = 0; k < 4; k++) {
        float Lu = 0, Ln = 0, Lsu = 0, Lsn = 0, Lssu = 0, L0 = bf_[k];
        for (int j = 0; j < 10; j++) {
            float wf1 = Wf[j * 4 + k];
            float wf2 = Wf[(10 + j) * 4 + k];
            float wf3 = Wf[(20 + j) * 4 + k];
            Lu   += p[j] * wf1 + rt[j] * wf2 + rh[j] * wf3;
            Ln   += st[j] * wf2 + (2.f * sh[j] + th[j]) * wf3;
            Lsu  += rt[j] * wf2 + 2.f * rh[j] * wf3;
            Lsn  += sh[j] * wf3;
            Lssu += rh[j] * wf3;
            L0   += q[j] * wf1 + (st[j] + dt[j]) * wf2 + (sh[j] + th[j] + dh[j]) * wf3;
        }
        Lout[0 * 4 + k] = Lu;  Lout[1 * 4 + k] = Ln;   Lout[2 * 4 + k] = Lsu;
        Lout[3 * 4 + k] = Lsn; Lout[4 * 4 + k] = Lssu; Lout[5 * 4 + k] = L0;
    }
}

// ---------------- F: logits -> softmax -> s ------------------------------------
__global__ __launch_bounds__(256) void finalk(
    const float* __restrict__ U, const float* __restrict__ NC,
    const float* __restrict__ SU, const float* __restrict__ SN,
    const float* __restrict__ SSU, const float* __restrict__ L,
    float4* __restrict__ sout)
{
    __shared__ float sL[24];
    if (threadIdx.x < 24) sL[threadIdx.x] = L[threadIdx.x];
    __syncthreads();
    int i = blockIdx.x * 256 + threadIdx.x;
    if (i >= NN) return;
    float u = U[i], n = NC[i], su = SU[i], sn = SN[i], ssu = SSU[i];
    float lg[4];
#pragma unroll
    for (int k = 0; k < 4; k++)
        lg[k] = sL[k] * u + sL[4 + k] * n + sL[8 + k] * su
              + sL[12 + k] * sn + sL[16 + k] * ssu + sL[20 + k];
    float mx = fmaxf(fmaxf(lg[0], lg[1]), fmaxf(lg[2], lg[3]));
    float e0 = __expf(lg[0] - mx), e1 = __expf(lg[1] - mx);
    float e2 = __expf(lg[2] - mx), e3 = __expf(lg[3] - mx);
    float inv = 1.f / (e0 + e1 + e2 + e3);
    sout[i] = make_float4(e0 * inv, e1 * inv, e2 * inv, e3 * inv);
}

// ---------------- mod_edge: pos, two_m, ds in one pass -------------------------
__global__ __launch_bounds__(256) void modk(
    const int* __restrict__ src, const int* __restrict__ dst,
    const float* __restrict__ w, const float4* __restrict__ sv,
    float* __restrict__ scal)   // scal[128]=two_m, [129]=pos, [132..135]=ds
{
    float acc[6] = {0, 0, 0, 0, 0, 0};  // wsum, pos, ds0..3
    int t = blockIdx.x * 256 + threadIdx.x;
    if (t < NEQ) {
        int4 s4 = reinterpret_cast<const int4*>(src)[t];
        int4 d4 = reinterpret_cast<const int4*>(dst)[t];
        float4 w4 = reinterpret_cast<const float4*>(w)[t];
        int ss[4] = {s4.x, s4.y, s4.z, s4.w};
        int dd[4] = {d4.x, d4.y, d4.z, d4.w};
        float ww[4] = {w4.x, w4.y, w4.z, w4.w};
#pragma unroll
        for (int e = 0; e < 4; e++) {
            float4 ua = sv[ss[e]];
            float4 ub = sv[dd[e]];
            float we = ww[e];
            acc[0] += we;
            acc[1] += we * (ua.x * ub.x + ua.y * ub.y + ua.z * ub.z + ua.w * ub.w);
            acc[2] += we * ua.x; acc[3] += we * ua.y;
            acc[4] += we * ua.z; acc[5] += we * ua.w;
        }
    }
    __shared__ float part[4][6];
    int lane = threadIdx.x & 63, wid = threadIdx.x >> 6;
#pragma unroll
    for (int k = 0; k < 6; k++) {
        float r = waveReduceF(acc[k]);
        if (lane == 0) part[wid][k] = r;
    }
    __syncthreads();
    if (threadIdx.x < 6) {
        float vsum = part[0][threadIdx.x] + part[1][threadIdx.x]
                   + part[2][threadIdx.x] + part[3][threadIdx.x];
        int off = (threadIdx.x == 0) ? 128 : (threadIdx.x == 1 ? 129 : 130 + threadIdx.x);
        atomicAdd(&scal[off], vsum);
    }
}

// ---------------- q ------------------------------------------------------------
__global__ void qk(const float* __restrict__ scal, float* __restrict__ out)
{
    if (threadIdx.x == 0) {
        float inv = 1.f / scal[128];
        float posv = scal[129] * inv;
        float acc = 0.f;
#pragma unroll
        for (int k = 0; k < 4; k++) {
            float d = scal[132 + k] * inv;
            acc += d * d;
        }
        out[(size_t)NN * 4] = posv - acc;
    }
}

extern "C" void kernel_launch(void* const* d_in, const int* in_sizes, int n_in,
                              void* d_out, int out_size, void* d_ws, size_t ws_size,
                              hipStream_t stream) {
    const float* x  = (const float*)d_in[0];
    const int*  ei  = (const int*)d_in[1];
    const int*  src = ei;
    const int*  dst = ei + NE;
    const float* w   = (const float*)d_in[2];
    const float* W1a = (const float*)d_in[3];  const float* b1a = (const float*)d_in[4];
    const float* W1b = (const float*)d_in[5];  const float* b1b = (const float*)d_in[6];
    const float* g1  = (const float*)d_in[7];  const float* be1 = (const float*)d_in[8];
    const float* W2a = (const float*)d_in[9];  const float* b2a = (const float*)d_in[10];
    const float* W2b = (const float*)d_in[11]; const float* b2b = (const float*)d_in[12];
    const float* g2  = (const float*)d_in[13]; const float* be2 = (const float*)d_in[14];
    const float* W3a = (const float*)d_in[15]; const float* b3a = (const float*)d_in[16];
    const float* W3b = (const float*)d_in[17]; const float* b3b = (const float*)d_in[18];
    const float* g3  = (const float*)d_in[19]; const float* be3 = (const float*)d_in[20];
    const float* Wf  = (const float*)d_in[21]; const float* bfb = (const float*)d_in[22];

    // workspace (floats):
    //  sc[0..511]: scalars — two_m @128, pos @129, ds[4] @132, L[24] @160,
    //              moments (20 doubles) @256 (as double*, 8B-aligned)
    //  then U[NN], NC[NN], SU[NN], SN[NN], SSU[NN], UN2[2*NN]
    float*  sc  = (float*)d_ws;
    double* dm  = (double*)(sc + 256);
    float*  U   = sc + 512;
    float*  NC  = U + NN;
    float*  SU  = NC + NN;
    float*  SN  = SU + NN;
    float*  SSU = SN + NN;
    float2* UN2 = (float2*)(SSU + NN);
    float*  sout = (float*)d_out;

    const int NB_N = (NN + 255) / 256;
    const int NB_E = (NEQ + 255) / 256;

    // zero scalars + moment accumulators + the 5 scatter tables (contiguous)
    hipMemsetAsync(sc, 0, (size_t)(512 + 5 * (size_t)NN) * sizeof(float), stream);

    edge1<<<NB_E, 256, 0, stream>>>(src, dst, x, U, NC);
    node1<<<NB_N, 256, 0, stream>>>(x, U, NC, UN2);
    edge2<<<NB_E, 256, 0, stream>>>(src, dst, UN2, SU, SN);
    edge3<<<NB_E, 256, 0, stream>>>(src, dst, SU, SSU);
    moments<<<NB_N, 256, 0, stream>>>(U, NC, SU, SN, SSU, dm);
    constk<<<1, 64, 0, stream>>>(W1a, b1a, W1b, b1b, g1, be1,
                                 W2a, b2a, W2b, b2b, g2, be2,
                                 W3a, b3a, W3b, b3b, g3, be3,
                                 Wf, bfb, dm, sc + 160);
    finalk<<<NB_N, 256, 0, stream>>>(U, NC, SU, SN, SSU, sc + 160, (float4*)sout);
    modk<<<NB_E, 256, 0, stream>>>(src, dst, w, (const float4*)sout, sc);
    qk<<<1, 64, 0, stream>>>(sc, sout);
}

// Round 5
// 1474.478 us; speedup vs baseline: 6.3389x; 1.5740x over previous
//
#include <hip/hip_runtime.h>

#define NN 500000
#define NE 8000000
#define NEQ (NE / 4)          // edges processed 4 per thread
#define BN_EPS 1e-5f

// packing scales: fields are exact integers inside the f64 mantissa
#define S1 4194304.f          // 2^22, edge1 low-field scale for (x+8)
#define INV_S1 (1.0 / 4194304.0)
#define S2 524288.f           // 2^19, edge2 low-field scale for (u+64)
#define INV_S2 (1.0 / 524288.0)

__device__ __forceinline__ float waveReduceF(float v) {
#pragma unroll
    for (int o = 32; o > 0; o >>= 1) v += __shfl_down(v, o, 64);
    return v;
}
__device__ __forceinline__ double waveReduceD(double v) {
#pragma unroll
    for (int o = 32; o > 0; o >>= 1) v += __shfl_down(v, o, 64);
    return v;
}

// ---------------- E1: D1[dst] += pack(1, x[src]) -------------------------------
__global__ __launch_bounds__(256) void edge1(
    const int* __restrict__ src, const int* __restrict__ dst,
    const float* __restrict__ x, double* __restrict__ D1)
{
    int t = blockIdx.x * 256 + threadIdx.x;
    if (t >= NEQ) return;
    int4 s4 = reinterpret_cast<const int4*>(src)[t];
    int4 d4 = reinterpret_cast<const int4*>(dst)[t];
    float x0 = x[s4.x], x1 = x[s4.y], x2 = x[s4.z], x3 = x[s4.w];
    // field = round((x+8)*2^22), count rides at bit 32; all-positive, exact ints
    double p0 = 4294967296.0 + (double)(long long)((x0 + 8.f) * S1 + 0.5f);
    double p1 = 4294967296.0 + (double)(long long)((x1 + 8.f) * S1 + 0.5f);
    double p2 = 4294967296.0 + (double)(long long)((x2 + 8.f) * S1 + 0.5f);
    double p3 = 4294967296.0 + (double)(long long)((x3 + 8.f) * S1 + 0.5f);
    atomicAdd(&D1[d4.x], p0); atomicAdd(&D1[d4.y], p1);
    atomicAdd(&D1[d4.z], p2); atomicAdd(&D1[d4.w], p3);
}

// ---------------- N1: decode D1 -> (u, n) --------------------------------------
__global__ __launch_bounds__(256) void node1(
    const float* __restrict__ x, const double* __restrict__ D1,
    float2* __restrict__ UN2)
{
    int i = blockIdx.x * 256 + threadIdx.x;
    if (i >= NN) return;
    long long I = (long long)D1[i];
    int n = (int)(I >> 32);
    long long f = I & 0xFFFFFFFFll;
    float U = (float)((double)f * INV_S1 - 8.0 * (double)n);
    UN2[i] = make_float2(x[i] + U, (float)n);
}

// ---------------- E2: D2[dst] += pack(n[src], u[src]) --------------------------
__global__ __launch_bounds__(256) void edge2(
    const int* __restrict__ src, const int* __restrict__ dst,
    const float2* __restrict__ UN2, double* __restrict__ D2)
{
    int t = blockIdx.x * 256 + threadIdx.x;
    if (t >= NEQ) return;
    int4 s4 = reinterpret_cast<const int4*>(src)[t];
    int4 d4 = reinterpret_cast<const int4*>(dst)[t];
    float2 a0 = UN2[s4.x], a1 = UN2[s4.y], a2 = UN2[s4.z], a3 = UN2[s4.w];
    double p0 = (double)(((long long)(int)a0.y << 32) + (long long)((a0.x + 64.f) * S2 + 0.5f));
    double p1 = (double)(((long long)(int)a1.y << 32) + (long long)((a1.x + 64.f) * S2 + 0.5f));
    double p2 = (double)(((long long)(int)a2.y << 32) + (long long)((a2.x + 64.f) * S2 + 0.5f));
    double p3 = (double)(((long long)(int)a3.y << 32) + (long long)((a3.x + 64.f) * S2 + 0.5f));
    atomicAdd(&D2[d4.x], p0); atomicAdd(&D2[d4.y], p1);
    atomicAdd(&D2[d4.z], p2); atomicAdd(&D2[d4.w], p3);
}

// ---------------- N2: decode D2 -> (su, sn) ------------------------------------
__global__ __launch_bounds__(256) void node2(
    const double* __restrict__ D2, const float2* __restrict__ UN2,
    float2* __restrict__ SUN)
{
    int i = blockIdx.x * 256 + threadIdx.x;
    if (i >= NN) return;
    long long I = (long long)D2[i];
    int sn = (int)(I >> 32);
    long long f = I & 0xFFFFFFFFll;
    float n = UN2[i].y;   // bias 64 was added once per incoming edge = n times
    float su = (float)((double)f * INV_S2 - 64.0 * (double)n);
    SUN[i] = make_float2(su, (float)sn);
}

// ---------------- E3: SSU[dst] += su[src] --------------------------------------
__global__ __launch_bounds__(256) void edge3(
    const int* __restrict__ src, const int* __restrict__ dst,
    const float2* __restrict__ SUN, float* __restrict__ SSU)
{
    int t = blockIdx.x * 256 + threadIdx.x;
    if (t >= NEQ) return;
    int4 s4 = reinterpret_cast<const int4*>(src)[t];
    int4 d4 = reinterpret_cast<const int4*>(dst)[t];
    float v0 = SUN[s4.x].x, v1 = SUN[s4.y].x, v2 = SUN[s4.z].x, v3 = SUN[s4.w].x;
    atomicAdd(&SSU[d4.x], v0); atomicAdd(&SSU[d4.y], v1);
    atomicAdd(&SSU[d4.z], v2); atomicAdd(&SSU[d4.w], v3);
}

// ---------------- M: first+second moments of (u,n,su,sn,ssu) in f64 ------------
__global__ __launch_bounds__(256) void moments(
    const float2* __restrict__ UN2, const float2* __restrict__ SUN,
    const float* __restrict__ SSU, double* __restrict__ dm)
{
    int i = blockIdx.x * 256 + threadIdx.x;
    double z[5] = {0, 0, 0, 0, 0};
    if (i < NN) {
        float2 un = UN2[i]; float2 ss = SUN[i];
        z[0] = (double)un.x; z[1] = (double)un.y; z[2] = (double)ss.x;
        z[3] = (double)ss.y; z[4] = (double)SSU[i];
    }
    double m[20];
#pragma unroll
    for (int a = 0; a < 5; a++) m[a] = z[a];
    int idx = 5;
#pragma unroll
    for (int a = 0; a < 5; a++)
#pragma unroll
        for (int b = a; b < 5; b++) m[idx++] = z[a] * z[b];

    __shared__ double part[4][20];
    int lane = threadIdx.x & 63, wid = threadIdx.x >> 6;
#pragma unroll
    for (int k = 0; k < 20; k++) {
        double r = waveReduceD(m[k]);
        if (lane == 0) part[wid][k] = r;
    }
    __syncthreads();
    if (threadIdx.x < 20)
        atomicAdd(&dm[threadIdx.x],
                  part[0][threadIdx.x] + part[1][threadIdx.x] +
                  part[2][threadIdx.x] + part[3][threadIdx.x]);
}

// ---------------- K: fold weights + moments into the 4x6 logit matrix ----------
__device__ void mm1010(const float* in, const float* Wa, const float* Wb, float* out)
{
    float t[10];
    for (int m = 0; m < 10; m++) {
        float acc = 0.f;
        for (int k = 0; k < 10; k++) acc += in[k] * Wa[k * 10 + m];
        t[m] = acc;
    }
    for (int j = 0; j < 10; j++) {
        float acc = 0.f;
        for (int m = 0; m < 10; m++) acc += t[m] * Wb[m * 10 + j];
        out[j] = acc;
    }
}

__global__ void constk(
    const float* __restrict__ W1a, const float* __restrict__ b1a,
    const float* __restrict__ W1b, const float* __restrict__ b1b,
    const float* __restrict__ g1, const float* __restrict__ be1,
    const float* __restrict__ W2a, const float* __restrict__ b2a,
    const float* __restrict__ W2b, const float* __restrict__ b2b,
    const float* __restrict__ g2, const float* __restrict__ be2,
    const float* __restrict__ W3a, const float* __restrict__ b3a,
    const float* __restrict__ W3b, const float* __restrict__ b3b,
    const float* __restrict__ g3, const float* __restrict__ be3,
    const float* __restrict__ Wf, const float* __restrict__ bf_,
    const double* __restrict__ dm, float* __restrict__ Lout)
{
    if (threadIdx.x != 0 || blockIdx.x != 0) return;
    const double invN = 1.0 / (double)NN;
    double E[5];
    for (int m = 0; m < 5; m++) E[m] = dm[m] * invN;
    double C[5][5];
    {
        int idx = 5;
        for (int a = 0; a < 5; a++)
            for (int b = a; b < 5; b++) {
                double c = dm[idx++] * invN - E[a] * E[b];
                C[a][b] = c; C[b][a] = c;
            }
    }
    // ----- layer 1: h1 = u*v + c1 -----
    float v[10], c1[10];
    for (int j = 0; j < 10; j++) {
        float av = 0.f, ac = 0.f;
        for (int k = 0; k < 10; k++) {
            av += W1a[k] * W1b[k * 10 + j];
            ac += b1a[k] * W1b[k * 10 + j];
        }
        v[j] = av; c1[j] = ac + b1b[j];
    }
    double Eu = E[0], Vu = C[0][0];
    float p[10], q[10];
    for (int j = 0; j < 10; j++) {
        float var1 = (float)(Vu * (double)v[j] * (double)v[j]);
        float sc1 = g1[j] * rsqrtf(var1 + BN_EPS);
        p[j] = sc1 * v[j];
        q[j] = be1[j] - (float)Eu * p[j];
    }
    // ----- layer 2: h2 = a*r + b*s + d2 ; a=u+su, b=1+n -----
    float r[10], s[10], d2[10];
    mm1010(p, W2a, W2b, r);
    mm1010(q, W2a, W2b, s);
    for (int j = 0; j < 10; j++) {
        float acc = b2b[j];
        for (int m = 0; m < 10; m++) acc += b2a[m] * W2b[m * 10 + j];
        d2[j] = acc;
    }
    double Ea = E[0] + E[2], Eb = 1.0 + E[1];
    double Va = C[0][0] + 2.0 * C[0][2] + C[2][2];
    double Vb = C[1][1];
    double Cab = C[0][1] + C[2][1];
    float rt[10], st[10], dt[10];
    for (int j = 0; j < 10; j++) {
        double rj = r[j], sj = s[j];
        float var2 = (float)(Va * rj * rj + Vb * sj * sj + 2.0 * Cab * rj * sj);
        float sc2 = g2[j] * rsqrtf(var2 + BN_EPS);
        rt[j] = sc2 * r[j];
        st[j] = sc2 * s[j];
        dt[j] = be2[j] - sc2 * (float)(Ea * rj + Eb * sj);
    }
    // ----- layer 3: h3 = A*r3 + B*s3 + C*t3 + d3 ; A=u+2su+ssu, B=1+2n+sn, Cc=1+n
    float r3[10], s3[10], t3[10], d3[10];
    mm1010(rt, W3a, W3b, r3);
    mm1010(st, W3a, W3b, s3);
    mm1010(dt, W3a, W3b, t3);
    for (int j = 0; j < 10; j++) {
        float acc = b3b[j];
        for (int m = 0; m < 10; m++) acc += b3a[m] * W3b[m * 10 + j];
        d3[j] = acc;
    }
    const double gA[5] = {1, 0, 2, 0, 1};
    const double gB[5] = {0, 2, 0, 1, 0};
    const double gC[5] = {0, 1, 0, 0, 0};
    double EA = E[0] + 2.0 * E[2] + E[4];
    double EB = 1.0 + 2.0 * E[1] + E[3];
    double EC = 1.0 + E[1];
    double VA = 0, VB = 0, VC = 0, CAB = 0, CAC = 0, CBC = 0;
    for (int a = 0; a < 5; a++)
        for (int b = 0; b < 5; b++) {
            double c = C[a][b];
            VA  += gA[a] * gA[b] * c;
            VB  += gB[a] * gB[b] * c;
            VC  += gC[a] * gC[b] * c;
            CAB += gA[a] * gB[b] * c;
            CAC += gA[a] * gC[b] * c;
            CBC += gB[a] * gC[b] * c;
        }
    float rh[10], sh[10], th[10], dh[10];
    for (int j = 0; j < 10; j++) {
        double rj = r3[j], sj = s3[j], tj = t3[j];
        float var3 = (float)(VA * rj * rj + VB * sj * sj + VC * tj * tj
                             + 2.0 * (CAB * rj * sj + CAC * rj * tj + CBC * sj * tj));
        float sc3 = g3[j] * rsqrtf(var3 + BN_EPS);
        rh[j] = sc3 * r3[j];
        sh[j] = sc3 * s3[j];
        th[j] = sc3 * t3[j];
        dh[j] = be3[j] - sc3 * (float)(EA * rj + EB * sj + EC * tj);
    }
    // ----- logits = Lu*u + Ln*n + Lsu*su + Lsn*sn + Lssu*ssu + L0 -----
    for (int k = 0; k < 4; k++) {
        float Lu = 0, Ln = 0, Lsu = 0, Lsn = 0, Lssu = 0, L0 = bf_[k];
        for (int j = 0; j < 10; j++) {
            float wf1 = Wf[j * 4 + k];
            float wf2 = Wf[(10 + j) * 4 + k];
            float wf3 = Wf[(20 + j) * 4 + k];
            Lu   += p[j] * wf1 + rt[j] * wf2 + rh[j] * wf3;
            Ln   += st[j] * wf2 + (2.f * sh[j] + th[j]) * wf3;
            Lsu  += rt[j] * wf2 + 2.f * rh[j] * wf3;
            Lsn  += sh[j] * wf3;
            Lssu += rh[j] * wf3;
            L0   += q[j] * wf1 + (st[j] + dt[j]) * wf2 + (sh[j] + th[j] + dh[j]) * wf3;
        }
        Lout[0 * 4 + k] = Lu;  Lout[1 * 4 + k] = Ln;   Lout[2 * 4 + k] = Lsu;
        Lout[3 * 4 + k] = Lsn; Lout[4 * 4 + k] = Lssu; Lout[5 * 4 + k] = L0;
    }
}

// ---------------- F: logits -> softmax -> s ------------------------------------
__global__ __launch_bounds__(256) void finalk(
    const float2* __restrict__ UN2, const float2* __restrict__ SUN,
    const float* __restrict__ SSU, const float* __restrict__ L,
    float4* __restrict__ sout)
{
    __shared__ float sL[24];
    if (threadIdx.x < 24) sL[threadIdx.x] = L[threadIdx.x];
    __syncthreads();
    int i = blockIdx.x * 256 + threadIdx.x;
    if (i >= NN) return;
    float2 un = UN2[i]; float2 ss = SUN[i];
    float u = un.x, n = un.y, su = ss.x, sn = ss.y, ssu = SSU[i];
    float lg[4];
#pragma unroll
    for (int k = 0; k < 4; k++)
        lg[k] = sL[k] * u + sL[4 + k] * n + sL[8 + k] * su
              + sL[12 + k] * sn + sL[16 + k] * ssu + sL[20 + k];
    float mx = fmaxf(fmaxf(lg[0], lg[1]), fmaxf(lg[2], lg[3]));
    float e0 = __expf(lg[0] - mx), e1 = __expf(lg[1] - mx);
    float e2 = __expf(lg[2] - mx), e3 = __expf(lg[3] - mx);
    float inv = 1.f / (e0 + e1 + e2 + e3);
    sout[i] = make_float4(e0 * inv, e1 * inv, e2 * inv, e3 * inv);
}

// ---------------- mod_edge: pos, two_m, ds in one pass -------------------------
__global__ __launch_bounds__(256) void modk(
    const int* __restrict__ src, const int* __restrict__ dst,
    const float* __restrict__ w, const float4* __restrict__ sv,
    float* __restrict__ scal)   // scal[128]=two_m, [129]=pos, [132..135]=ds
{
    float acc[6] = {0, 0, 0, 0, 0, 0};  // wsum, pos, ds0..3
    int t = blockIdx.x * 256 + threadIdx.x;
    if (t < NEQ) {
        int4 s4 = reinterpret_cast<const int4*>(src)[t];
        int4 d4 = reinterpret_cast<const int4*>(dst)[t];
        float4 w4 = reinterpret_cast<const float4*>(w)[t];
        int ss[4] = {s4.x, s4.y, s4.z, s4.w};
        int dd[4] = {d4.x, d4.y, d4.z, d4.w};
        float ww[4] = {w4.x, w4.y, w4.z, w4.w};
#pragma unroll
        for (int e = 0; e < 4; e++) {
            float4 ua = sv[ss[e]];
            float4 ub = sv[dd[e]];
            float we = ww[e];
            acc[0] += we;
            acc[1] += we * (ua.x * ub.x + ua.y * ub.y + ua.z * ub.z + ua.w * ub.w);
            acc[2] += we * ua.x; acc[3] += we * ua.y;
            acc[4] += we * ua.z; acc[5] += we * ua.w;
        }
    }
    __shared__ float part[4][6];
    int lane = threadIdx.x & 63, wid = threadIdx.x >> 6;
#pragma unroll
    for (int k = 0; k < 6; k++) {
        float r = waveReduceF(acc[k]);
        if (lane == 0) part[wid][k] = r;
    }
    __syncthreads();
    if (threadIdx.x < 6) {
        float vsum = part[0][threadIdx.x] + part[1][threadIdx.x]
                   + part[2][threadIdx.x] + part[3][threadIdx.x];
        int off = (threadIdx.x == 0) ? 128 : (threadIdx.x == 1 ? 129 : 130 + threadIdx.x);
        atomicAdd(&scal[off], vsum);
    }
}

// ---------------- q ------------------------------------------------------------
__global__ void qk(const float* __restrict__ scal, float* __restrict__ out)
{
    if (threadIdx.x == 0) {
        float inv = 1.f / scal[128];
        float posv = scal[129] * inv;
        float acc = 0.f;
#pragma unroll
        for (int k = 0; k < 4; k++) {
            float d = scal[132 + k] * inv;
            acc += d * d;
        }
        out[(size_t)NN * 4] = posv - acc;
    }
}

extern "C" void kernel_launch(void* const* d_in, const int* in_sizes, int n_in,
                              void* d_out, int out_size, void* d_ws, size_t ws_size,
                              hipStream_t stream) {
    const float* x  = (const float*)d_in[0];
    const int*  ei  = (const int*)d_in[1];
    const int*  src = ei;
    const int*  dst = ei + NE;
    const float* w   = (const float*)d_in[2];
    const float* W1a = (const float*)d_in[3];  const float* b1a = (const float*)d_in[4];
    const float* W1b = (const float*)d_in[5];  const float* b1b = (const float*)d_in[6];
    const float* g1  = (const float*)d_in[7];  const float* be1 = (const float*)d_in[8];
    const float* W2a = (const float*)d_in[9];  const float* b2a = (const float*)d_in[10];
    const float* W2b = (const float*)d_in[11]; const float* b2b = (const float*)d_in[12];
    const float* g2  = (const float*)d_in[13]; const float* be2 = (const float*)d_in[14];
    const float* W3a = (const float*)d_in[15]; const float* b3a = (const float*)d_in[16];
    const float* W3b = (const float*)d_in[17]; const float* b3b = (const float*)d_in[18];
    const float* g3  = (const float*)d_in[19]; const float* be3 = (const float*)d_in[20];
    const float* Wf  = (const float*)d_in[21]; const float* bfb = (const float*)d_in[22];

    // workspace:
    //  sc[0..511] floats: two_m @128, pos @129, ds[4] @132, L[24] @160,
    //                     moments (20 doubles) @ sc+256
    //  D1[NN] double | D2[NN] double | SSU[NN] float | UN2[NN] float2 | SUN[NN] float2
    float*  sc  = (float*)d_ws;
    double* dm  = (double*)(sc + 256);
    double* D1  = (double*)(sc + 512);
    double* D2  = D1 + NN;
    float*  SSU = (float*)(D2 + NN);
    float2* UN2 = (float2*)(SSU + NN);
    float2* SUN = UN2 + NN;
    float*  sout = (float*)d_out;

    const int NB_N = (NN + 255) / 256;
    const int NB_E = (NEQ + 255) / 256;

    // zero scalars + D1 + D2 + SSU (contiguous: 2KB + 4MB + 4MB + 2MB)
    hipMemsetAsync(sc, 0, 512 * sizeof(float) + (size_t)NN * 20, stream);

    edge1<<<NB_E, 256, 0, stream>>>(src, dst, x, D1);
    node1<<<NB_N, 256, 0, stream>>>(x, D1, UN2);
    edge2<<<NB_E, 256, 0, stream>>>(src, dst, UN2, D2);
    node2<<<NB_N, 256, 0, stream>>>(D2, UN2, SUN);
    edge3<<<NB_E, 256, 0, stream>>>(src, dst, SUN, SSU);
    moments<<<NB_N, 256, 0, stream>>>(UN2, SUN, SSU, dm);
    constk<<<1, 64, 0, stream>>>(W1a, b1a, W1b, b1b, g1, be1,
                                 W2a, b2a, W2b, b2b, g2, be2,
                                 W3a, b3a, W3b, b3b, g3, be3,
                                 Wf, bfb, dm, sc + 160);
    finalk<<<NB_N, 256, 0, stream>>>(UN2, SUN, SSU, sc + 160, (float4*)sout);
    modk<<<NB_E, 256, 0, stream>>>(src, dst, w, (const float4*)sout, sc);
    qk<<<1, 64, 0, stream>>>(sc, sout);
}

// Round 6
// 739.537 us; speedup vs baseline: 12.6384x; 1.9938x over previous
//
#include <hip/hip_runtime.h>

#define NN 500000
#define NE 8000000
#define NB 62            // buckets of 8192 nodes: 62*8192 = 507904 >= NN
#define BSH 13
#define BSZ 8192
#define M 4              // slices (blocks) per bucket
#define NAGG (NB * M)    // 248 aggregation blocks
#define BN_EPS 1e-5f

__device__ __forceinline__ float waveReduceF(float v) {
#pragma unroll
    for (int o = 32; o > 0; o >>= 1) v += __shfl_down(v, o, 64);
    return v;
}
__device__ __forceinline__ double waveReduceD(double v) {
#pragma unroll
    for (int o = 32; o > 0; o >>= 1) v += __shfl_down(v, o, 64);
    return v;
}

// ---------------- bucketize step 1: per-bucket edge counts ---------------------
__global__ __launch_bounds__(512) void countk(const int* __restrict__ dst,
                                              int* __restrict__ cnt)
{
    __shared__ int h[NB];
    if (threadIdx.x < NB) h[threadIdx.x] = 0;
    __syncthreads();
    int base_e = blockIdx.x * 4096 + threadIdx.x * 8;
#pragma unroll
    for (int k = 0; k < 8; k++) {
        int e = base_e + k;
        if (e < NE) atomicAdd(&h[dst[e] >> BSH], 1);
    }
    __syncthreads();
    if (threadIdx.x < NB) {
        int v = h[threadIdx.x];
        if (v) atomicAdd(&cnt[threadIdx.x], v);
    }
}

// ---------------- bucketize step 2: exclusive scan (62 values) -----------------
__global__ void scank(const int* __restrict__ cnt, int* __restrict__ base,
                      int* __restrict__ cur)
{
    if (threadIdx.x == 0 && blockIdx.x == 0) {
        int acc = 0;
        for (int b = 0; b < NB; b++) { base[b] = acc; cur[b] = acc; acc += cnt[b]; }
    }
}

// ---------------- bucketize step 3: scatter (entry, w) into buckets ------------
__global__ __launch_bounds__(512) void scatterk(
    const int* __restrict__ src, const int* __restrict__ dst,
    const float* __restrict__ w, int* __restrict__ cur, uint2* __restrict__ pairs)
{
    __shared__ int h[NB];
    __shared__ int lb[NB];
    if (threadIdx.x < NB) h[threadIdx.x] = 0;
    __syncthreads();
    int base_e = blockIdx.x * 4096 + threadIdx.x * 8;
    int rk[8], bk[8];
    unsigned en[8], wb[8];
#pragma unroll
    for (int k = 0; k < 8; k++) {
        int e = base_e + k;
        if (e < NE) {
            int d = dst[e];
            int b = d >> BSH;
            bk[k] = b;
            en[k] = ((unsigned)(d & (BSZ - 1)) << 19) | (unsigned)src[e];
            wb[k] = __float_as_uint(w[e]);
            rk[k] = atomicAdd(&h[b], 1);
        } else bk[k] = -1;
    }
    __syncthreads();
    if (threadIdx.x < NB) lb[threadIdx.x] = atomicAdd(&cur[threadIdx.x], h[threadIdx.x]);
    __syncthreads();
#pragma unroll
    for (int k = 0; k < 8; k++)
        if (bk[k] >= 0) pairs[(size_t)lb[bk[k]] + rk[k]] = make_uint2(en[k], wb[k]);
}

// ---------------- agg pass 1: LDS tables (sum x, count) ------------------------
__global__ __launch_bounds__(1024) void agg1k(
    const uint2* __restrict__ pairs, const int* __restrict__ base,
    const int* __restrict__ cnt, const float* __restrict__ x,
    float* __restrict__ slab)
{
    extern __shared__ float t[];   // [0..BSZ)=sum x, [BSZ..2BSZ)=count
    for (int j = threadIdx.x; j < 2 * BSZ; j += 1024) t[j] = 0.f;
    __syncthreads();
    int B = blockIdx.x / M, sl = blockIdx.x % M;
    int b0 = base[B], len = cnt[B];
    int seg = (len + M - 1) / M;
    int lo = b0 + sl * seg;
    int hi = lo + seg, e1 = b0 + len;
    if (hi > e1) hi = e1;
    for (int idx = lo + threadIdx.x; idx < hi; idx += 1024) {
        uint2 p = pairs[idx];
        int s = p.x & 524287u;
        int dl = p.x >> 19;
        atomicAdd(&t[dl], x[s]);
        atomicAdd(&t[BSZ + dl], 1.f);
    }
    __syncthreads();
    float* sb = slab + (size_t)blockIdx.x * (2 * BSZ);
    for (int j = threadIdx.x; j < 2 * BSZ; j += 1024) sb[j] = t[j];
}

__global__ __launch_bounds__(256) void mergeN1(
    const float* __restrict__ slab, const float* __restrict__ x,
    float2* __restrict__ UN2)
{
    int i = blockIdx.x * 256 + threadIdx.x;
    if (i >= NN) return;
    int B = i >> BSH, low = i & (BSZ - 1);
    float sx = 0.f, cn = 0.f;
#pragma unroll
    for (int m = 0; m < M; m++) {
        const float* sb = slab + (size_t)(B * M + m) * (2 * BSZ);
        sx += sb[low];
        cn += sb[BSZ + low];
    }
    UN2[i] = make_float2(x[i] + sx, cn);
}

// ---------------- agg pass 2: LDS tables (sum u, sum n) ------------------------
__global__ __launch_bounds__(1024) void agg2k(
    const uint2* __restrict__ pairs, const int* __restrict__ base,
    const int* __restrict__ cnt, const float2* __restrict__ UN2,
    float* __restrict__ slab)
{
    extern __shared__ float t[];
    for (int j = threadIdx.x; j < 2 * BSZ; j += 1024) t[j] = 0.f;
    __syncthreads();
    int B = blockIdx.x / M, sl = blockIdx.x % M;
    int b0 = base[B], len = cnt[B];
    int seg = (len + M - 1) / M;
    int lo = b0 + sl * seg;
    int hi = lo + seg, e1 = b0 + len;
    if (hi > e1) hi = e1;
    for (int idx = lo + threadIdx.x; idx < hi; idx += 1024) {
        uint2 p = pairs[idx];
        int s = p.x & 524287u;
        int dl = p.x >> 19;
        float2 v = UN2[s];
        atomicAdd(&t[dl], v.x);
        atomicAdd(&t[BSZ + dl], v.y);
    }
    __syncthreads();
    float* sb = slab + (size_t)blockIdx.x * (2 * BSZ);
    for (int j = threadIdx.x; j < 2 * BSZ; j += 1024) sb[j] = t[j];
}

__global__ __launch_bounds__(256) void mergeN2(
    const float* __restrict__ slab, float2* __restrict__ SUN)
{
    int i = blockIdx.x * 256 + threadIdx.x;
    if (i >= NN) return;
    int B = i >> BSH, low = i & (BSZ - 1);
    float su = 0.f, sn = 0.f;
#pragma unroll
    for (int m = 0; m < M; m++) {
        const float* sb = slab + (size_t)(B * M + m) * (2 * BSZ);
        su += sb[low];
        sn += sb[BSZ + low];
    }
    SUN[i] = make_float2(su, sn);
}

// ---------------- agg pass 3: LDS table (sum su) -------------------------------
__global__ __launch_bounds__(1024) void agg3k(
    const uint2* __restrict__ pairs, const int* __restrict__ base,
    const int* __restrict__ cnt, const float2* __restrict__ SUN,
    float* __restrict__ slab)
{
    extern __shared__ float t[];   // [0..BSZ)
    for (int j = threadIdx.x; j < BSZ; j += 1024) t[j] = 0.f;
    __syncthreads();
    int B = blockIdx.x / M, sl = blockIdx.x % M;
    int b0 = base[B], len = cnt[B];
    int seg = (len + M - 1) / M;
    int lo = b0 + sl * seg;
    int hi = lo + seg, e1 = b0 + len;
    if (hi > e1) hi = e1;
    for (int idx = lo + threadIdx.x; idx < hi; idx += 1024) {
        uint2 p = pairs[idx];
        int s = p.x & 524287u;
        int dl = p.x >> 19;
        atomicAdd(&t[dl], SUN[s].x);
    }
    __syncthreads();
    float* sb = slab + (size_t)blockIdx.x * BSZ;
    for (int j = threadIdx.x; j < BSZ; j += 1024) sb[j] = t[j];
}

__global__ __launch_bounds__(256) void mergeN3(
    const float* __restrict__ slab, float* __restrict__ SSU)
{
    int i = blockIdx.x * 256 + threadIdx.x;
    if (i >= NN) return;
    int B = i >> BSH, low = i & (BSZ - 1);
    float s = 0.f;
#pragma unroll
    for (int m = 0; m < M; m++) s += slab[(size_t)(B * M + m) * BSZ + low];
    SSU[i] = s;
}

// ---------------- M: first+second moments of (u,n,su,sn,ssu) in f64 ------------
__global__ __launch_bounds__(256) void moments(
    const float2* __restrict__ UN2, const float2* __restrict__ SUN,
    const float* __restrict__ SSU, double* __restrict__ dm)
{
    int i = blockIdx.x * 256 + threadIdx.x;
    double z[5] = {0, 0, 0, 0, 0};
    if (i < NN) {
        float2 un = UN2[i]; float2 ss = SUN[i];
        z[0] = (double)un.x; z[1] = (double)un.y; z[2] = (double)ss.x;
        z[3] = (double)ss.y; z[4] = (double)SSU[i];
    }
    double m[20];
#pragma unroll
    for (int a = 0; a < 5; a++) m[a] = z[a];
    int idx = 5;
#pragma unroll
    for (int a = 0; a < 5; a++)
#pragma unroll
        for (int b = a; b < 5; b++) m[idx++] = z[a] * z[b];

    __shared__ double part[4][20];
    int lane = threadIdx.x & 63, wid = threadIdx.x >> 6;
#pragma unroll
    for (int k = 0; k < 20; k++) {
        double r = waveReduceD(m[k]);
        if (lane == 0) part[wid][k] = r;
    }
    __syncthreads();
    if (threadIdx.x < 20)
        atomicAdd(&dm[threadIdx.x],
                  part[0][threadIdx.x] + part[1][threadIdx.x] +
                  part[2][threadIdx.x] + part[3][threadIdx.x]);
}

// ---------------- K: fold weights + moments into the 4x6 logit matrix ----------
__device__ void mm1010(const float* in, const float* Wa, const float* Wb, float* out)
{
    float t[10];
    for (int m = 0; m < 10; m++) {
        float acc = 0.f;
        for (int k = 0; k < 10; k++) acc += in[k] * Wa[k * 10 + m];
        t[m] = acc;
    }
    for (int j = 0; j < 10; j++) {
        float acc = 0.f;
        for (int m = 0; m < 10; m++) acc += t[m] * Wb[m * 10 + j];
        out[j] = acc;
    }
}

__global__ void constk(
    const float* __restrict__ W1a, const float* __restrict__ b1a,
    const float* __restrict__ W1b, const float* __restrict__ b1b,
    const float* __restrict__ g1, const float* __restrict__ be1,
    const float* __restrict__ W2a, const float* __restrict__ b2a,
    const float* __restrict__ W2b, const float* __restrict__ b2b,
    const float* __restrict__ g2, const float* __restrict__ be2,
    const float* __restrict__ W3a, const float* __restrict__ b3a,
    const float* __restrict__ W3b, const float* __restrict__ b3b,
    const float* __restrict__ g3, const float* __restrict__ be3,
    const float* __restrict__ Wf, const float* __restrict__ bf_,
    const double* __restrict__ dm, float* __restrict__ Lout)
{
    if (threadIdx.x != 0 || blockIdx.x != 0) return;
    const double invN = 1.0 / (double)NN;
    double E[5];
    for (int m = 0; m < 5; m++) E[m] = dm[m] * invN;
    double C[5][5];
    {
        int idx = 5;
        for (int a = 0; a < 5; a++)
            for (int b = a; b < 5; b++) {
                double c = dm[idx++] * invN - E[a] * E[b];
                C[a][b] = c; C[b][a] = c;
            }
    }
    float v[10], c1[10];
    for (int j = 0; j < 10; j++) {
        float av = 0.f, ac = 0.f;
        for (int k = 0; k < 10; k++) {
            av += W1a[k] * W1b[k * 10 + j];
            ac += b1a[k] * W1b[k * 10 + j];
        }
        v[j] = av; c1[j] = ac + b1b[j];
    }
    double Eu = E[0], Vu = C[0][0];
    float p[10], q[10];
    for (int j = 0; j < 10; j++) {
        float var1 = (float)(Vu * (double)v[j] * (double)v[j]);
        float sc1 = g1[j] * rsqrtf(var1 + BN_EPS);
        p[j] = sc1 * v[j];
        q[j] = be1[j] - (float)Eu * p[j];
    }
    float r[10], s[10], d2[10];
    mm1010(p, W2a, W2b, r);
    mm1010(q, W2a, W2b, s);
    for (int j = 0; j < 10; j++) {
        float acc = b2b[j];
        for (int m = 0; m < 10; m++) acc += b2a[m] * W2b[m * 10 + j];
        d2[j] = acc;
    }
    double Ea = E[0] + E[2], Eb = 1.0 + E[1];
    double Va = C[0][0] + 2.0 * C[0][2] + C[2][2];
    double Vb = C[1][1];
    double Cab = C[0][1] + C[2][1];
    float rt[10], st[10], dt[10];
    for (int j = 0; j < 10; j++) {
        double rj = r[j], sj = s[j];
        float var2 = (float)(Va * rj * rj + Vb * sj * sj + 2.0 * Cab * rj * sj);
        float sc2 = g2[j] * rsqrtf(var2 + BN_EPS);
        rt[j] = sc2 * r[j];
        st[j] = sc2 * s[j];
        dt[j] = be2[j] - sc2 * (float)(Ea * rj + Eb * sj);
    }
    float r3[10], s3[10], t3[10], d3[10];
    mm1010(rt, W3a, W3b, r3);
    mm1010(st, W3a, W3b, s3);
    mm1010(dt, W3a, W3b, t3);
    for (int j = 0; j < 10; j++) {
        float acc = b3b[j];
        for (int m = 0; m < 10; m++) acc += b3a[m] * W3b[m * 10 + j];
        d3[j] = acc;
    }
    const double gA[5] = {1, 0, 2, 0, 1};
    const double gB[5] = {0, 2, 0, 1, 0};
    const double gC[5] = {0, 1, 0, 0, 0};
    double EA = E[0] + 2.0 * E[2] + E[4];
    double EB = 1.0 + 2.0 * E[1] + E[3];
    double EC = 1.0 + E[1];
    double VA = 0, VB = 0, VC = 0, CAB = 0, CAC = 0, CBC = 0;
    for (int a = 0; a < 5; a++)
        for (int b = 0; b < 5; b++) {
            double c = C[a][b];
            VA  += gA[a] * gA[b] * c;
            VB  += gB[a] * gB[b] * c;
            VC  += gC[a] * gC[b] * c;
            CAB += gA[a] * gB[b] * c;
            CAC += gA[a] * gC[b] * c;
            CBC += gB[a] * gC[b] * c;
        }
    float rh[10], sh[10], th[10], dh[10];
    for (int j = 0; j < 10; j++) {
        double rj = r3[j], sj = s3[j], tj = t3[j];
        float var3 = (float)(VA * rj * rj + VB * sj * sj + VC * tj * tj
                             + 2.0 * (CAB * rj * sj + CAC * rj * tj + CBC * sj * tj));
        float sc3 = g3[j] * rsqrtf(var3 + BN_EPS);
        rh[j] = sc3 * r3[j];
        sh[j] = sc3 * s3[j];
        th[j] = sc3 * t3[j];
        dh[j] = be3[j] - sc3 * (float)(EA * rj + EB * sj + EC * tj);
    }
    for (int k = 0; k < 4; k++) {
        float Lu = 0, Ln = 0, Lsu = 0, Lsn = 0, Lssu = 0, L0 = bf_[k];
        for (int j = 0; j < 10; j++) {
            float wf1 = Wf[j * 4 + k];
            float wf2 = Wf[(10 + j) * 4 + k];
            float wf3 = Wf[(20 + j) * 4 + k];
            Lu   += p[j] * wf1 + rt[j] * wf2 + rh[j] * wf3;
            Ln   += st[j] * wf2 + (2.f * sh[j] + th[j]) * wf3;
            Lsu  += rt[j] * wf2 + 2.f * rh[j] * wf3;
            Lsn  += sh[j] * wf3;
            Lssu += rh[j] * wf3;
            L0   += q[j] * wf1 + (st[j] + dt[j]) * wf2 + (sh[j] + th[j] + dh[j]) * wf3;
        }
        Lout[0 * 4 + k] = Lu;  Lout[1 * 4 + k] = Ln;   Lout[2 * 4 + k] = Lsu;
        Lout[3 * 4 + k] = Lsn; Lout[4 * 4 + k] = Lssu; Lout[5 * 4 + k] = L0;
    }
}

// ---------------- F: logits -> softmax -> s ------------------------------------
__global__ __launch_bounds__(256) void finalk(
    const float2* __restrict__ UN2, const float2* __restrict__ SUN,
    const float* __restrict__ SSU, const float* __restrict__ L,
    float4* __restrict__ sout)
{
    __shared__ float sL[24];
    if (threadIdx.x < 24) sL[threadIdx.x] = L[threadIdx.x];
    __syncthreads();
    int i = blockIdx.x * 256 + threadIdx.x;
    if (i >= NN) return;
    float2 un = UN2[i]; float2 ss = SUN[i];
    float u = un.x, n = un.y, su = ss.x, sn = ss.y, ssu = SSU[i];
    float lg[4];
#pragma unroll
    for (int k = 0; k < 4; k++)
        lg[k] = sL[k] * u + sL[4 + k] * n + sL[8 + k] * su
              + sL[12 + k] * sn + sL[16 + k] * ssu + sL[20 + k];
    float mx = fmaxf(fmaxf(lg[0], lg[1]), fmaxf(lg[2], lg[3]));
    float e0 = __expf(lg[0] - mx), e1 = __expf(lg[1] - mx);
    float e2 = __expf(lg[2] - mx), e3 = __expf(lg[3] - mx);
    float inv = 1.f / (e0 + e1 + e2 + e3);
    sout[i] = make_float4(e0 * inv, e1 * inv, e2 * inv, e3 * inv);
}

// ---------------- modk over buckets: two_m, pos, ds ----------------------------
__global__ __launch_bounds__(1024) void modk(
    const uint2* __restrict__ pairs, const int* __restrict__ base,
    const int* __restrict__ cnt, const float4* __restrict__ sv,
    float* __restrict__ scal)   // scal[128]=two_m, [129]=pos, [132..135]=ds
{
    int B = blockIdx.x / M, sl = blockIdx.x % M;
    int b0 = base[B], len = cnt[B];
    int seg = (len + M - 1) / M;
    int lo = b0 + sl * seg;
    int hi = lo + seg, e1 = b0 + len;
    if (hi > e1) hi = e1;
    float acc[6] = {0, 0, 0, 0, 0, 0};
    for (int idx = lo + (int)threadIdx.x; idx < hi; idx += 1024) {
        uint2 p = pairs[idx];
        int s = p.x & 524287u;
        int d = (B << BSH) + (int)(p.x >> 19);
        float we = __uint_as_float(p.y);
        float4 ua = sv[s];
        float4 ub = sv[d];
        acc[0] += we;
        acc[1] += we * (ua.x * ub.x + ua.y * ub.y + ua.z * ub.z + ua.w * ub.w);
        acc[2] += we * ua.x; acc[3] += we * ua.y;
        acc[4] += we * ua.z; acc[5] += we * ua.w;
    }
    __shared__ float part[16][6];
    int lane = threadIdx.x & 63, wid = threadIdx.x >> 6;
#pragma unroll
    for (int k = 0; k < 6; k++) {
        float r = waveReduceF(acc[k]);
        if (lane == 0) part[wid][k] = r;
    }
    __syncthreads();
    if (threadIdx.x < 6) {
        float vsum = 0.f;
#pragma unroll
        for (int wdi = 0; wdi < 16; wdi++) vsum += part[wdi][threadIdx.x];
        int off = (threadIdx.x == 0) ? 128 : (threadIdx.x == 1 ? 129 : 130 + threadIdx.x);
        atomicAdd(&scal[off], vsum);
    }
}

// ---------------- q ------------------------------------------------------------
__global__ void qk(const float* __restrict__ scal, float* __restrict__ out)
{
    if (threadIdx.x == 0) {
        float inv = 1.f / scal[128];
        float posv = scal[129] * inv;
        float acc = 0.f;
#pragma unroll
        for (int k = 0; k < 4; k++) {
            float d = scal[132 + k] * inv;
            acc += d * d;
        }
        out[(size_t)NN * 4] = posv - acc;
    }
}

extern "C" void kernel_launch(void* const* d_in, const int* in_sizes, int n_in,
                              void* d_out, int out_size, void* d_ws, size_t ws_size,
                              hipStream_t stream) {
    const float* x  = (const float*)d_in[0];
    const int*  ei  = (const int*)d_in[1];
    const int*  src = ei;
    const int*  dst = ei + NE;
    const float* w   = (const float*)d_in[2];
    const float* W1a = (const float*)d_in[3];  const float* b1a = (const float*)d_in[4];
    const float* W1b = (const float*)d_in[5];  const float* b1b = (const float*)d_in[6];
    const float* g1  = (const float*)d_in[7];  const float* be1 = (const float*)d_in[8];
    const float* W2a = (const float*)d_in[9];  const float* b2a = (const float*)d_in[10];
    const float* W2b = (const float*)d_in[11]; const float* b2b = (const float*)d_in[12];
    const float* g2  = (const float*)d_in[13]; const float* be2 = (const float*)d_in[14];
    const float* W3a = (const float*)d_in[15]; const float* b3a = (const float*)d_in[16];
    const float* W3b = (const float*)d_in[17]; const float* b3b = (const float*)d_in[18];
    const float* g3  = (const float*)d_in[19]; const float* be3 = (const float*)d_in[20];
    const float* Wf  = (const float*)d_in[21]; const float* bfb = (const float*)d_in[22];

    // workspace layout:
    //  sc[0..511] floats: two_m@128, pos@129, ds@132..135, L@160..183,
    //    count@192 (int[62]), base@256 (int[62]), cursor@320 (int[62]),
    //    dm (20 doubles) @ float-idx 384 (byte 1536, 8B-aligned)
    //  pairs uint2[NE] (64MB) | slab float[NAGG*2*BSZ] (16.25MB) |
    //  UN2 float2[NN] | SUN float2[NN] | SSU float[NN]
    float*  sc   = (float*)d_ws;
    int*    sci  = (int*)d_ws;
    double* dm   = (double*)(sc + 384);
    uint2*  pairs = (uint2*)(sc + 512);
    float*  slab  = (float*)(pairs + NE);
    float2* UN2   = (float2*)(slab + (size_t)NAGG * 2 * BSZ);
    float2* SUN   = UN2 + NN;
    float*  SSU   = (float*)(SUN + NN);
    float*  sout  = (float*)d_out;

    const int NB_N  = (NN + 255) / 256;
    const int NB_E4 = (NE + 4095) / 4096;

    hipMemsetAsync(sc, 0, 2048, stream);

    // bucketize once (dst -> 62 buckets of 8192 nodes)
    countk<<<NB_E4, 512, 0, stream>>>(dst, sci + 192);
    scank<<<1, 64, 0, stream>>>(sci + 192, sci + 256, sci + 320);
    scatterk<<<NB_E4, 512, 0, stream>>>(src, dst, w, sci + 320, pairs);

    // three aggregation rounds via LDS privatization (no global atomics)
    agg1k<<<NAGG, 1024, 65536, stream>>>(pairs, sci + 256, sci + 192, x, slab);
    mergeN1<<<NB_N, 256, 0, stream>>>(slab, x, UN2);
    agg2k<<<NAGG, 1024, 65536, stream>>>(pairs, sci + 256, sci + 192, UN2, slab);
    mergeN2<<<NB_N, 256, 0, stream>>>(slab, SUN);
    agg3k<<<NAGG, 1024, 32768, stream>>>(pairs, sci + 256, sci + 192, SUN, slab);
    mergeN3<<<NB_N, 256, 0, stream>>>(slab, SSU);

    // moments -> closed-form logit matrix -> softmax -> modularity
    moments<<<NB_N, 256, 0, stream>>>(UN2, SUN, SSU, dm);
    constk<<<1, 64, 0, stream>>>(W1a, b1a, W1b, b1b, g1, be1,
                                 W2a, b2a, W2b, b2b, g2, be2,
                                 W3a, b3a, W3b, b3b, g3, be3,
                                 Wf, bfb, dm, sc + 160);
    finalk<<<NB_N, 256, 0, stream>>>(UN2, SUN, SSU, sc + 160, (float4*)sout);
    modk<<<NAGG, 1024, 0, stream>>>(pairs, sci + 256, sci + 192,
                                    (const float4*)sout, sc);
    qk<<<1, 64, 0, stream>>>(sc, sout);
}

// Round 7
// 702.817 us; speedup vs baseline: 13.2987x; 1.0522x over previous
//
#include <hip/hip_runtime.h>
#include <hip/hip_bf16.h>

#define NN 500000
#define NE 8000000
#define NB 123           // buckets of 4096 nodes: 123*4096 = 503808 >= NN
#define BSH 12
#define BSZ 4096
#define M 8              // slices (blocks) per bucket
#define NAGG (NB * M)    // 984 blocks
#define BN_EPS 1e-5f

__device__ __forceinline__ float waveReduceF(float v) {
#pragma unroll
    for (int o = 32; o > 0; o >>= 1) v += __shfl_down(v, o, 64);
    return v;
}
__device__ __forceinline__ double waveReduceD(double v) {
#pragma unroll
    for (int o = 32; o > 0; o >>= 1) v += __shfl_down(v, o, 64);
    return v;
}
__device__ __forceinline__ float u2f(unsigned short u) {
    return __bfloat162float(__builtin_bit_cast(__hip_bfloat16, u));
}
__device__ __forceinline__ unsigned short f2u(float f) {
    return __builtin_bit_cast(unsigned short, __float2bfloat16(f));
}

// ---------------- bucketize step 1: per-bucket edge counts ---------------------
__global__ __launch_bounds__(512) void countk(const int* __restrict__ dst,
                                              int* __restrict__ cnt)
{
    __shared__ int h[NB];
    if (threadIdx.x < NB) h[threadIdx.x] = 0;
    __syncthreads();
    int base_e = blockIdx.x * 4096 + threadIdx.x * 8;
#pragma unroll
    for (int k = 0; k < 8; k++) {
        int e = base_e + k;
        if (e < NE) atomicAdd(&h[dst[e] >> BSH], 1);
    }
    __syncthreads();
    if (threadIdx.x < NB) {
        int v = h[threadIdx.x];
        if (v) atomicAdd(&cnt[threadIdx.x], v);
    }
}

// ---------------- bucketize step 2: exclusive scan -----------------------------
__global__ void scank(const int* __restrict__ cnt, int* __restrict__ base,
                      int* __restrict__ cur)
{
    if (threadIdx.x == 0 && blockIdx.x == 0) {
        int acc = 0;
        for (int b = 0; b < NB; b++) { base[b] = acc; cur[b] = acc; acc += cnt[b]; }
    }
}

// ---------------- bucketize step 3: scatter entry + bf16 weight ----------------
__global__ __launch_bounds__(512) void scatterk(
    const int* __restrict__ src, const int* __restrict__ dst,
    const float* __restrict__ w, int* __restrict__ cur,
    unsigned* __restrict__ pairs, unsigned short* __restrict__ wp)
{
    __shared__ int h[NB];
    __shared__ int lb[NB];
    if (threadIdx.x < NB) h[threadIdx.x] = 0;
    __syncthreads();
    int base_e = blockIdx.x * 4096 + threadIdx.x * 8;
    int rk[8], bk[8];
    unsigned en[8];
    unsigned short wb[8];
#pragma unroll
    for (int k = 0; k < 8; k++) {
        int e = base_e + k;
        if (e < NE) {
            int d = dst[e];
            int b = d >> BSH;
            bk[k] = b;
            en[k] = ((unsigned)(d & (BSZ - 1)) << 19) | (unsigned)src[e];
            wb[k] = f2u(w[e]);
            rk[k] = atomicAdd(&h[b], 1);
        } else bk[k] = -1;
    }
    __syncthreads();
    if (threadIdx.x < NB) lb[threadIdx.x] = atomicAdd(&cur[threadIdx.x], h[threadIdx.x]);
    __syncthreads();
#pragma unroll
    for (int k = 0; k < 8; k++)
        if (bk[k] >= 0) {
            size_t pos = (size_t)lb[bk[k]] + rk[k];
            pairs[pos] = en[k];
            wp[pos] = wb[k];
        }
}

// ---------------- agg pass 1: LDS tables (sum x, count) ------------------------
__global__ __launch_bounds__(512) void agg1k(
    const unsigned* __restrict__ pairs, const int* __restrict__ base,
    const int* __restrict__ cnt, const float* __restrict__ x,
    float* __restrict__ slab)
{
    extern __shared__ float t[];   // [0..BSZ)=sum x, [BSZ..2BSZ)=count
    for (int j = threadIdx.x; j < 2 * BSZ; j += 512) t[j] = 0.f;
    __syncthreads();
    int B = blockIdx.x / M, sl = blockIdx.x % M;
    int b0 = base[B], len = cnt[B];
    int seg = (len + M - 1) / M;
    int lo = b0 + sl * seg;
    int hi = lo + seg, e1 = b0 + len;
    if (hi > e1) hi = e1;
    for (int idx = lo + (int)threadIdx.x; idx < hi; idx += 512) {
        unsigned p = pairs[idx];
        int s = p & 524287u;
        int dl = p >> 19;
        atomicAdd(&t[dl], x[s]);
        atomicAdd(&t[BSZ + dl], 1.f);
    }
    __syncthreads();
    float* sb = slab + (size_t)blockIdx.x * (2 * BSZ);
    for (int j = threadIdx.x; j < 2 * BSZ; j += 512) sb[j] = t[j];
}

__global__ __launch_bounds__(256) void mergeN1(
    const float* __restrict__ slab, const float* __restrict__ x,
    float2* __restrict__ UN2)
{
    int i = blockIdx.x * 256 + threadIdx.x;
    if (i >= NN) return;
    int B = i >> BSH, low = i & (BSZ - 1);
    float sx = 0.f, cn = 0.f;
#pragma unroll
    for (int m = 0; m < M; m++) {
        const float* sb = slab + (size_t)(B * M + m) * (2 * BSZ);
        sx += sb[low];
        cn += sb[BSZ + low];
    }
    UN2[i] = make_float2(x[i] + sx, cn);
}

// ---------------- agg pass 2: LDS tables (sum u, sum n) ------------------------
__global__ __launch_bounds__(512) void agg2k(
    const unsigned* __restrict__ pairs, const int* __restrict__ base,
    const int* __restrict__ cnt, const float2* __restrict__ UN2,
    float* __restrict__ slab)
{
    extern __shared__ float t[];
    for (int j = threadIdx.x; j < 2 * BSZ; j += 512) t[j] = 0.f;
    __syncthreads();
    int B = blockIdx.x / M, sl = blockIdx.x % M;
    int b0 = base[B], len = cnt[B];
    int seg = (len + M - 1) / M;
    int lo = b0 + sl * seg;
    int hi = lo + seg, e1 = b0 + len;
    if (hi > e1) hi = e1;
    for (int idx = lo + (int)threadIdx.x; idx < hi; idx += 512) {
        unsigned p = pairs[idx];
        int s = p & 524287u;
        int dl = p >> 19;
        float2 v = UN2[s];
        atomicAdd(&t[dl], v.x);
        atomicAdd(&t[BSZ + dl], v.y);
    }
    __syncthreads();
    float* sb = slab + (size_t)blockIdx.x * (2 * BSZ);
    for (int j = threadIdx.x; j < 2 * BSZ; j += 512) sb[j] = t[j];
}

__global__ __launch_bounds__(256) void mergeN2(
    const float* __restrict__ slab, float2* __restrict__ SUN)
{
    int i = blockIdx.x * 256 + threadIdx.x;
    if (i >= NN) return;
    int B = i >> BSH, low = i & (BSZ - 1);
    float su = 0.f, sn = 0.f;
#pragma unroll
    for (int m = 0; m < M; m++) {
        const float* sb = slab + (size_t)(B * M + m) * (2 * BSZ);
        su += sb[low];
        sn += sb[BSZ + low];
    }
    SUN[i] = make_float2(su, sn);
}

// ---------------- agg pass 3: LDS table (sum su) -------------------------------
__global__ __launch_bounds__(512) void agg3k(
    const unsigned* __restrict__ pairs, const int* __restrict__ base,
    const int* __restrict__ cnt, const float2* __restrict__ SUN,
    float* __restrict__ slab)
{
    extern __shared__ float t[];   // [0..BSZ)
    for (int j = threadIdx.x; j < BSZ; j += 512) t[j] = 0.f;
    __syncthreads();
    int B = blockIdx.x / M, sl = blockIdx.x % M;
    int b0 = base[B], len = cnt[B];
    int seg = (len + M - 1) / M;
    int lo = b0 + sl * seg;
    int hi = lo + seg, e1 = b0 + len;
    if (hi > e1) hi = e1;
    for (int idx = lo + (int)threadIdx.x; idx < hi; idx += 512) {
        unsigned p = pairs[idx];
        int s = p & 524287u;
        int dl = p >> 19;
        atomicAdd(&t[dl], SUN[s].x);
    }
    __syncthreads();
    float* sb = slab + (size_t)blockIdx.x * BSZ;
    for (int j = threadIdx.x; j < BSZ; j += 512) sb[j] = t[j];
}

// ---------------- fused: merge SSU + f64 moments of (u,n,su,sn,ssu) ------------
__global__ __launch_bounds__(256) void m3mom(
    const float* __restrict__ slab, const float2* __restrict__ UN2,
    const float2* __restrict__ SUN, float* __restrict__ SSU,
    double* __restrict__ dm)
{
    int i = blockIdx.x * 256 + threadIdx.x;
    double z[5] = {0, 0, 0, 0, 0};
    if (i < NN) {
        int B = i >> BSH, low = i & (BSZ - 1);
        float ssu = 0.f;
#pragma unroll
        for (int m = 0; m < M; m++) ssu += slab[(size_t)(B * M + m) * BSZ + low];
        SSU[i] = ssu;
        float2 un = UN2[i]; float2 ss = SUN[i];
        z[0] = (double)un.x; z[1] = (double)un.y; z[2] = (double)ss.x;
        z[3] = (double)ss.y; z[4] = (double)ssu;
    }
    double m[20];
#pragma unroll
    for (int a = 0; a < 5; a++) m[a] = z[a];
    int idx = 5;
#pragma unroll
    for (int a = 0; a < 5; a++)
#pragma unroll
        for (int b = a; b < 5; b++) m[idx++] = z[a] * z[b];

    __shared__ double part[4][20];
    int lane = threadIdx.x & 63, wid = threadIdx.x >> 6;
#pragma unroll
    for (int k = 0; k < 20; k++) {
        double r = waveReduceD(m[k]);
        if (lane == 0) part[wid][k] = r;
    }
    __syncthreads();
    if (threadIdx.x < 20)
        atomicAdd(&dm[threadIdx.x],
                  part[0][threadIdx.x] + part[1][threadIdx.x] +
                  part[2][threadIdx.x] + part[3][threadIdx.x]);
}

// ---------------- K: fold weights + moments into the 4x6 logit matrix ----------
__device__ void mm1010(const float* in, const float* Wa, const float* Wb, float* out)
{
    float t[10];
    for (int m = 0; m < 10; m++) {
        float acc = 0.f;
        for (int k = 0; k < 10; k++) acc += in[k] * Wa[k * 10 + m];
        t[m] = acc;
    }
    for (int j = 0; j < 10; j++) {
        float acc = 0.f;
        for (int m = 0; m < 10; m++) acc += t[m] * Wb[m * 10 + j];
        out[j] = acc;
    }
}

__global__ void constk(
    const float* __restrict__ W1a, const float* __restrict__ b1a,
    const float* __restrict__ W1b, const float* __restrict__ b1b,
    const float* __restrict__ g1, const float* __restrict__ be1,
    const float* __restrict__ W2a, const float* __restrict__ b2a,
    const float* __restrict__ W2b, const float* __restrict__ b2b,
    const float* __restrict__ g2, const float* __restrict__ be2,
    const float* __restrict__ W3a, const float* __restrict__ b3a,
    const float* __restrict__ W3b, const float* __restrict__ b3b,
    const float* __restrict__ g3, const float* __restrict__ be3,
    const float* __restrict__ Wf, const float* __restrict__ bf_,
    const double* __restrict__ dm, float* __restrict__ Lout)
{
    if (threadIdx.x != 0 || blockIdx.x != 0) return;
    const double invN = 1.0 / (double)NN;
    double E[5];
    for (int m = 0; m < 5; m++) E[m] = dm[m] * invN;
    double C[5][5];
    {
        int idx = 5;
        for (int a = 0; a < 5; a++)
            for (int b = a; b < 5; b++) {
                double c = dm[idx++] * invN - E[a] * E[b];
                C[a][b] = c; C[b][a] = c;
            }
    }
    float v[10], c1[10];
    for (int j = 0; j < 10; j++) {
        float av = 0.f, ac = 0.f;
        for (int k = 0; k < 10; k++) {
            av += W1a[k] * W1b[k * 10 + j];
            ac += b1a[k] * W1b[k * 10 + j];
        }
        v[j] = av; c1[j] = ac + b1b[j];
    }
    double Eu = E[0], Vu = C[0][0];
    float p[10], q[10];
    for (int j = 0; j < 10; j++) {
        float var1 = (float)(Vu * (double)v[j] * (double)v[j]);
        float sc1 = g1[j] * rsqrtf(var1 + BN_EPS);
        p[j] = sc1 * v[j];
        q[j] = be1[j] - (float)Eu * p[j];
    }
    float r[10], s[10], d2[10];
    mm1010(p, W2a, W2b, r);
    mm1010(q, W2a, W2b, s);
    for (int j = 0; j < 10; j++) {
        float acc = b2b[j];
        for (int m = 0; m < 10; m++) acc += b2a[m] * W2b[m * 10 + j];
        d2[j] = acc;
    }
    double Ea = E[0] + E[2], Eb = 1.0 + E[1];
    double Va = C[0][0] + 2.0 * C[0][2] + C[2][2];
    double Vb = C[1][1];
    double Cab = C[0][1] + C[2][1];
    float rt[10], st[10], dt[10];
    for (int j = 0; j < 10; j++) {
        double rj = r[j], sj = s[j];
        float var2 = (float)(Va * rj * rj + Vb * sj * sj + 2.0 * Cab * rj * sj);
        float sc2 = g2[j] * rsqrtf(var2 + BN_EPS);
        rt[j] = sc2 * r[j];
        st[j] = sc2 * s[j];
        dt[j] = be2[j] - sc2 * (float)(Ea * rj + Eb * sj);
    }
    float r3[10], s3[10], t3[10], d3[10];
    mm1010(rt, W3a, W3b, r3);
    mm1010(st, W3a, W3b, s3);
    mm1010(dt, W3a, W3b, t3);
    for (int j = 0; j < 10; j++) {
        float acc = b3b[j];
        for (int m = 0; m < 10; m++) acc += b3a[m] * W3b[m * 10 + j];
        d3[j] = acc;
    }
    const double gA[5] = {1, 0, 2, 0, 1};
    const double gB[5] = {0, 2, 0, 1, 0};
    const double gC[5] = {0, 1, 0, 0, 0};
    double EA = E[0] + 2.0 * E[2] + E[4];
    double EB = 1.0 + 2.0 * E[1] + E[3];
    double EC = 1.0 + E[1];
    double VA = 0, VB = 0, VC = 0, CAB = 0, CAC = 0, CBC = 0;
    for (int a = 0; a < 5; a++)
        for (int b = 0; b < 5; b++) {
            double c = C[a][b];
            VA  += gA[a] * gA[b] * c;
            VB  += gB[a] * gB[b] * c;
            VC  += gC[a] * gC[b] * c;
            CAB += gA[a] * gB[b] * c;
            CAC += gA[a] * gC[b] * c;
            CBC += gB[a] * gC[b] * c;
        }
    float rh[10], sh[10], th[10], dh[10];
    for (int j = 0; j < 10; j++) {
        double rj = r3[j], sj = s3[j], tj = t3[j];
        float var3 = (float)(VA * rj * rj + VB * sj * sj + VC * tj * tj
                             + 2.0 * (CAB * rj * sj + CAC * rj * tj + CBC * sj * tj));
        float sc3 = g3[j] * rsqrtf(var3 + BN_EPS);
        rh[j] = sc3 * r3[j];
        sh[j] = sc3 * s3[j];
        th[j] = sc3 * t3[j];
        dh[j] = be3[j] - sc3 * (float)(EA * rj + EB * sj + EC * tj);
    }
    for (int k = 0; k < 4; k++) {
        float Lu = 0, Ln = 0, Lsu = 0, Lsn = 0, Lssu = 0, L0 = bf_[k];
        for (int j = 0; j < 10; j++) {
            float wf1 = Wf[j * 4 + k];
            float wf2 = Wf[(10 + j) * 4 + k];
            float wf3 = Wf[(20 + j) * 4 + k];
            Lu   += p[j] * wf1 + rt[j] * wf2 + rh[j] * wf3;
            Ln   += st[j] * wf2 + (2.f * sh[j] + th[j]) * wf3;
            Lsu  += rt[j] * wf2 + 2.f * rh[j] * wf3;
            Lsn  += sh[j] * wf3;
            Lssu += rh[j] * wf3;
            L0   += q[j] * wf1 + (st[j] + dt[j]) * wf2 + (sh[j] + th[j] + dh[j]) * wf3;
        }
        Lout[0 * 4 + k] = Lu;  Lout[1 * 4 + k] = Ln;   Lout[2 * 4 + k] = Lsu;
        Lout[3 * 4 + k] = Lsn; Lout[4 * 4 + k] = Lssu; Lout[5 * 4 + k] = L0;
    }
}

// ---------------- F: logits -> softmax -> s (f32 out + bf16 side table) --------
__global__ __launch_bounds__(256) void finalk(
    const float2* __restrict__ UN2, const float2* __restrict__ SUN,
    const float* __restrict__ SSU, const float* __restrict__ L,
    float4* __restrict__ sout, ushort4* __restrict__ sbf)
{
    __shared__ float sL[24];
    if (threadIdx.x < 24) sL[threadIdx.x] = L[threadIdx.x];
    __syncthreads();
    int i = blockIdx.x * 256 + threadIdx.x;
    if (i >= NN) return;
    float2 un = UN2[i]; float2 ss = SUN[i];
    float u = un.x, n = un.y, su = ss.x, sn = ss.y, ssu = SSU[i];
    float lg[4];
#pragma unroll
    for (int k = 0; k < 4; k++)
        lg[k] = sL[k] * u + sL[4 + k] * n + sL[8 + k] * su
              + sL[12 + k] * sn + sL[16 + k] * ssu + sL[20 + k];
    float mx = fmaxf(fmaxf(lg[0], lg[1]), fmaxf(lg[2], lg[3]));
    float e0 = __expf(lg[0] - mx), e1 = __expf(lg[1] - mx);
    float e2 = __expf(lg[2] - mx), e3 = __expf(lg[3] - mx);
    float inv = 1.f / (e0 + e1 + e2 + e3);
    float s0 = e0 * inv, s1 = e1 * inv, s2 = e2 * inv, s3 = e3 * inv;
    sout[i] = make_float4(s0, s1, s2, s3);
    ushort4 pk; pk.x = f2u(s0); pk.y = f2u(s1); pk.z = f2u(s2); pk.w = f2u(s3);
    sbf[i] = pk;
}

// ---------------- modk over buckets: two_m, pos, ds (bf16 gathers) -------------
__global__ __launch_bounds__(512) void modk(
    const unsigned* __restrict__ pairs, const unsigned short* __restrict__ wp,
    const int* __restrict__ base, const int* __restrict__ cnt,
    const ushort4* __restrict__ sbf, float* __restrict__ scal)
{
    int B = blockIdx.x / M, sl = blockIdx.x % M;
    int b0 = base[B], len = cnt[B];
    int seg = (len + M - 1) / M;
    int lo = b0 + sl * seg;
    int hi = lo + seg, e1 = b0 + len;
    if (hi > e1) hi = e1;
    float acc[6] = {0, 0, 0, 0, 0, 0};
    for (int idx = lo + (int)threadIdx.x; idx < hi; idx += 512) {
        unsigned p = pairs[idx];
        int s = p & 524287u;
        int d = (B << BSH) + (int)(p >> 19);
        float we = u2f(wp[idx]);
        ushort4 ua = sbf[s];
        ushort4 ub = sbf[d];
        float ax = u2f(ua.x), ay = u2f(ua.y), az = u2f(ua.z), aw = u2f(ua.w);
        float bx = u2f(ub.x), by = u2f(ub.y), bz = u2f(ub.z), bw = u2f(ub.w);
        acc[0] += we;
        acc[1] += we * (ax * bx + ay * by + az * bz + aw * bw);
        acc[2] += we * ax; acc[3] += we * ay;
        acc[4] += we * az; acc[5] += we * aw;
    }
    __shared__ float part[8][6];
    int lane = threadIdx.x & 63, wid = threadIdx.x >> 6;
#pragma unroll
    for (int k = 0; k < 6; k++) {
        float r = waveReduceF(acc[k]);
        if (lane == 0) part[wid][k] = r;
    }
    __syncthreads();
    if (threadIdx.x < 6) {
        float vsum = 0.f;
#pragma unroll
        for (int wdi = 0; wdi < 8; wdi++) vsum += part[wdi][threadIdx.x];
        int off = (threadIdx.x == 0) ? 128 : (threadIdx.x == 1 ? 129 : 130 + threadIdx.x);
        atomicAdd(&scal[off], vsum);
    }
}

// ---------------- q ------------------------------------------------------------
__global__ void qk(const float* __restrict__ scal, float* __restrict__ out)
{
    if (threadIdx.x == 0) {
        float inv = 1.f / scal[128];
        float posv = scal[129] * inv;
        float acc = 0.f;
#pragma unroll
        for (int k = 0; k < 4; k++) {
            float d = scal[132 + k] * inv;
            acc += d * d;
        }
        out[(size_t)NN * 4] = posv - acc;
    }
}

extern "C" void kernel_launch(void* const* d_in, const int* in_sizes, int n_in,
                              void* d_out, int out_size, void* d_ws, size_t ws_size,
                              hipStream_t stream) {
    const float* x  = (const float*)d_in[0];
    const int*  ei  = (const int*)d_in[1];
    const int*  src = ei;
    const int*  dst = ei + NE;
    const float* w   = (const float*)d_in[2];
    const float* W1a = (const float*)d_in[3];  const float* b1a = (const float*)d_in[4];
    const float* W1b = (const float*)d_in[5];  const float* b1b = (const float*)d_in[6];
    const float* g1  = (const float*)d_in[7];  const float* be1 = (const float*)d_in[8];
    const float* W2a = (const float*)d_in[9];  const float* b2a = (const float*)d_in[10];
    const float* W2b = (const float*)d_in[11]; const float* b2b = (const float*)d_in[12];
    const float* g2  = (const float*)d_in[13]; const float* be2 = (const float*)d_in[14];
    const float* W3a = (const float*)d_in[15]; const float* b3a = (const float*)d_in[16];
    const float* W3b = (const float*)d_in[17]; const float* b3b = (const float*)d_in[18];
    const float* g3  = (const float*)d_in[19]; const float* be3 = (const float*)d_in[20];
    const float* Wf  = (const float*)d_in[21]; const float* bfb = (const float*)d_in[22];

    // workspace layout:
    //  floats sc[0..1023]: two_m@128, pos@129, ds@132..135, L@160..183,
    //    dm (20 doubles) @ float-idx 384 (byte 1536),
    //    count ints @ sci[576], base @ sci[704], cur @ sci[832]
    //  byte 4096: pairs uint[NE] (32MB) | wp ushort[NE] (16MB) |
    //    slab float[NAGG*2*BSZ] (32.25MB) | UN2 float2[NN] | SUN float2[NN] |
    //    SSU float[NN] | sbf ushort4[NN]
    float*  sc   = (float*)d_ws;
    int*    sci  = (int*)d_ws;
    double* dm   = (double*)(sc + 384);
    unsigned* pairs = (unsigned*)(sc + 1024);
    unsigned short* wp = (unsigned short*)(pairs + NE);
    float*  slab = (float*)(wp + NE);
    float2* UN2  = (float2*)(slab + (size_t)NAGG * 2 * BSZ);
    float2* SUN  = UN2 + NN;
    float*  SSU  = (float*)(SUN + NN);
    ushort4* sbf = (ushort4*)(SSU + NN);
    float*  sout = (float*)d_out;

    const int NB_N  = (NN + 255) / 256;
    const int NB_E4 = (NE + 4095) / 4096;

    hipMemsetAsync(sc, 0, 4096, stream);

    // bucketize once (dst -> 123 buckets of 4096 nodes)
    countk<<<NB_E4, 512, 0, stream>>>(dst, sci + 576);
    scank<<<1, 64, 0, stream>>>(sci + 576, sci + 704, sci + 832);
    scatterk<<<NB_E4, 512, 0, stream>>>(src, dst, w, sci + 832, pairs, wp);

    // three aggregation rounds via LDS privatization (no global atomics)
    agg1k<<<NAGG, 512, 32768, stream>>>(pairs, sci + 704, sci + 576, x, slab);
    mergeN1<<<NB_N, 256, 0, stream>>>(slab, x, UN2);
    agg2k<<<NAGG, 512, 32768, stream>>>(pairs, sci + 704, sci + 576, UN2, slab);
    mergeN2<<<NB_N, 256, 0, stream>>>(slab, SUN);
    agg3k<<<NAGG, 512, 16384, stream>>>(pairs, sci + 704, sci + 576, SUN, slab);
    m3mom<<<NB_N, 256, 0, stream>>>(slab, UN2, SUN, SSU, dm);

    // closed-form logit matrix -> softmax -> modularity
    constk<<<1, 64, 0, stream>>>(W1a, b1a, W1b, b1b, g1, be1,
                                 W2a, b2a, W2b, b2b, g2, be2,
                                 W3a, b3a, W3b, b3b, g3, be3,
                                 Wf, bfb, dm, sc + 160);
    finalk<<<NB_N, 256, 0, stream>>>(UN2, SUN, SSU, sc + 160, (float4*)sout, sbf);
    modk<<<NAGG, 512, 0, stream>>>(pairs, wp, sci + 704, sci + 576, sbf, sc);
    qk<<<1, 64, 0, stream>>>(sc, sout);
}

// Round 8
// 641.513 us; speedup vs baseline: 14.5696x; 1.0956x over previous
//
#include <hip/hip_runtime.h>
#include <hip/hip_bf16.h>

#define NN 500000
#define NE 8000000
#define NB 123           // buckets of 4096 nodes: 123*4096 = 503808 >= NN
#define BSH 12
#define BSZ 4096
#define M 8              // slices (blocks) per bucket
#define NAGG (NB * M)    // 984 blocks
#define BN_EPS 1e-5f

__device__ __forceinline__ float waveReduceF(float v) {
#pragma unroll
    for (int o = 32; o > 0; o >>= 1) v += __shfl_down(v, o, 64);
    return v;
}
__device__ __forceinline__ double waveReduceD(double v) {
#pragma unroll
    for (int o = 32; o > 0; o >>= 1) v += __shfl_down(v, o, 64);
    return v;
}
__device__ __forceinline__ float u2f(unsigned short u) {
    return __bfloat162float(__builtin_bit_cast(__hip_bfloat16, u));
}
__device__ __forceinline__ unsigned short f2u(float f) {
    return __builtin_bit_cast(unsigned short, __float2bfloat16(f));
}

// ---------------- bucketize step 1: per-bucket edge counts (per-wave hists) ----
__global__ __launch_bounds__(512) void countk(const int4* __restrict__ dst4,
                                              int* __restrict__ cnt)
{
    __shared__ int h[8][128];
    int tid = threadIdx.x, wv = tid >> 6;
    for (int j = tid; j < 8 * 128; j += 512) (&h[0][0])[j] = 0;
    __syncthreads();
#pragma unroll
    for (int k = 0; k < 2; k++) {
        int q = blockIdx.x * 1024 + k * 512 + tid;
        if (q < NE / 4) {
            int4 d4 = dst4[q];
            atomicAdd(&h[wv][d4.x >> BSH], 1);
            atomicAdd(&h[wv][d4.y >> BSH], 1);
            atomicAdd(&h[wv][d4.z >> BSH], 1);
            atomicAdd(&h[wv][d4.w >> BSH], 1);
        }
    }
    __syncthreads();
    if (tid < NB) {
        int s = 0;
#pragma unroll
        for (int w = 0; w < 8; w++) s += h[w][tid];
        if (s) atomicAdd(&cnt[tid], s);
    }
}

// ---------------- bucketize step 2: exclusive scan -----------------------------
__global__ void scank(const int* __restrict__ cnt, int* __restrict__ base,
                      int* __restrict__ cur)
{
    if (threadIdx.x == 0 && blockIdx.x == 0) {
        int acc = 0;
        for (int b = 0; b < NB; b++) { base[b] = acc; cur[b] = acc; acc += cnt[b]; }
    }
}

// ---------------- bucketize step 3: block counting sort, coalesced emit --------
__global__ __launch_bounds__(512) void scatterk(
    const int4* __restrict__ src4, const int4* __restrict__ dst4,
    const float4* __restrict__ w4, int* __restrict__ cur,
    unsigned* __restrict__ pairs, unsigned short* __restrict__ wp)
{
    __shared__ unsigned sEnt[4096];        // 16 KB
    __shared__ unsigned short sW[4096];    // 8 KB
    __shared__ unsigned char sB[4096];     // 4 KB
    __shared__ int h[8][128];              // per-wave histograms
    __shared__ int wOff[8][128];           // cross-wave prefix per bucket
    __shared__ int bOff[128];              // block-local bucket prefix
    __shared__ int lb[128];                // global base for this block per bucket
    __shared__ int tot[128];

    int tid = threadIdx.x, wv = tid >> 6;
    for (int j = tid; j < 8 * 128; j += 512) (&h[0][0])[j] = 0;
    __syncthreads();

    unsigned en[8]; unsigned short wb[8]; int rb[8];   // rk<<8 | b, or -1
#pragma unroll
    for (int k = 0; k < 2; k++) {
        int q = blockIdx.x * 1024 + k * 512 + tid;
        if (q < NE / 4) {
            int4 s4 = src4[q]; int4 d4 = dst4[q]; float4 ww = w4[q];
            int ss[4] = {s4.x, s4.y, s4.z, s4.w};
            int dd[4] = {d4.x, d4.y, d4.z, d4.w};
            float fw[4] = {ww.x, ww.y, ww.z, ww.w};
#pragma unroll
            for (int i = 0; i < 4; i++) {
                int d = dd[i], b = d >> BSH;
                en[k * 4 + i] = ((unsigned)(d & (BSZ - 1)) << 19) | (unsigned)ss[i];
                wb[k * 4 + i] = f2u(fw[i]);
                int rk = atomicAdd(&h[wv][b], 1);
                rb[k * 4 + i] = (rk << 8) | b;
            }
        } else {
#pragma unroll
            for (int i = 0; i < 4; i++) rb[k * 4 + i] = -1;
        }
    }
    __syncthreads();
    if (tid < NB) {
        int acc = 0;
#pragma unroll
        for (int w = 0; w < 8; w++) { wOff[w][tid] = acc; acc += h[w][tid]; }
        tot[tid] = acc;
        lb[tid] = atomicAdd(&cur[tid], acc);
    }
    __syncthreads();
    if (tid == 0) {
        int acc = 0;
        for (int b = 0; b < NB; b++) { bOff[b] = acc; acc += tot[b]; }
    }
    __syncthreads();
#pragma unroll
    for (int k = 0; k < 8; k++) {
        if (rb[k] >= 0) {
            int b = rb[k] & 255, rk = rb[k] >> 8;
            int pos = bOff[b] + wOff[wv][b] + rk;
            sEnt[pos] = en[k]; sW[pos] = wb[k]; sB[pos] = (unsigned char)b;
        }
    }
    __syncthreads();
    int nE = NE - blockIdx.x * 4096; if (nE > 4096) nE = 4096;
    for (int j = tid; j < nE; j += 512) {
        int b = sB[j];
        int glob = lb[b] + (j - bOff[b]);
        pairs[glob] = sEnt[j];
        wp[glob] = sW[j];
    }
}

// ---------------- agg pass 1: LDS tables (sum x, count) ------------------------
__global__ __launch_bounds__(512) void agg1k(
    const unsigned* __restrict__ pairs, const int* __restrict__ base,
    const int* __restrict__ cnt, const float* __restrict__ x,
    float* __restrict__ slab)
{
    extern __shared__ float t[];   // [0..BSZ)=sum x, [BSZ..2BSZ)=count
    for (int j = threadIdx.x; j < 2 * BSZ; j += 512) t[j] = 0.f;
    __syncthreads();
    int B = blockIdx.x / M, sl = blockIdx.x % M;
    int b0 = base[B], len = cnt[B];
    int seg = (len + M - 1) / M;
    int lo = b0 + sl * seg;
    int hi = lo + seg, e1 = b0 + len;
    if (hi > e1) hi = e1;
    for (int idx = lo + (int)threadIdx.x; idx < hi; idx += 512) {
        unsigned p = pairs[idx];
        int s = p & 524287u;
        int dl = p >> 19;
        atomicAdd(&t[dl], x[s]);
        atomicAdd(&t[BSZ + dl], 1.f);
    }
    __syncthreads();
    float* sb = slab + (size_t)blockIdx.x * (2 * BSZ);
    for (int j = threadIdx.x; j < 2 * BSZ; j += 512) sb[j] = t[j];
}

__global__ __launch_bounds__(256) void mergeN1(
    const float* __restrict__ slab, const float* __restrict__ x,
    float2* __restrict__ UN2)
{
    int i = blockIdx.x * 256 + threadIdx.x;
    if (i >= NN) return;
    int B = i >> BSH, low = i & (BSZ - 1);
    float sx = 0.f, cn = 0.f;
#pragma unroll
    for (int m = 0; m < M; m++) {
        const float* sb = slab + (size_t)(B * M + m) * (2 * BSZ);
        sx += sb[low];
        cn += sb[BSZ + low];
    }
    UN2[i] = make_float2(x[i] + sx, cn);
}

// ---------------- agg pass 2: LDS tables (sum u, sum n) ------------------------
__global__ __launch_bounds__(512) void agg2k(
    const unsigned* __restrict__ pairs, const int* __restrict__ base,
    const int* __restrict__ cnt, const float2* __restrict__ UN2,
    float* __restrict__ slab)
{
    extern __shared__ float t[];
    for (int j = threadIdx.x; j < 2 * BSZ; j += 512) t[j] = 0.f;
    __syncthreads();
    int B = blockIdx.x / M, sl = blockIdx.x % M;
    int b0 = base[B], len = cnt[B];
    int seg = (len + M - 1) / M;
    int lo = b0 + sl * seg;
    int hi = lo + seg, e1 = b0 + len;
    if (hi > e1) hi = e1;
    for (int idx = lo + (int)threadIdx.x; idx < hi; idx += 512) {
        unsigned p = pairs[idx];
        int s = p & 524287u;
        int dl = p >> 19;
        float2 v = UN2[s];
        atomicAdd(&t[dl], v.x);
        atomicAdd(&t[BSZ + dl], v.y);
    }
    __syncthreads();
    float* sb = slab + (size_t)blockIdx.x * (2 * BSZ);
    for (int j = threadIdx.x; j < 2 * BSZ; j += 512) sb[j] = t[j];
}

__global__ __launch_bounds__(256) void mergeN2(
    const float* __restrict__ slab, float2* __restrict__ SUN)
{
    int i = blockIdx.x * 256 + threadIdx.x;
    if (i >= NN) return;
    int B = i >> BSH, low = i & (BSZ - 1);
    float su = 0.f, sn = 0.f;
#pragma unroll
    for (int m = 0; m < M; m++) {
        const float* sb = slab + (size_t)(B * M + m) * (2 * BSZ);
        su += sb[low];
        sn += sb[BSZ + low];
    }
    SUN[i] = make_float2(su, sn);
}

// ---------------- agg pass 3: LDS table (sum su) -------------------------------
__global__ __launch_bounds__(512) void agg3k(
    const unsigned* __restrict__ pairs, const int* __restrict__ base,
    const int* __restrict__ cnt, const float2* __restrict__ SUN,
    float* __restrict__ slab)
{
    extern __shared__ float t[];   // [0..BSZ)
    for (int j = threadIdx.x; j < BSZ; j += 512) t[j] = 0.f;
    __syncthreads();
    int B = blockIdx.x / M, sl = blockIdx.x % M;
    int b0 = base[B], len = cnt[B];
    int seg = (len + M - 1) / M;
    int lo = b0 + sl * seg;
    int hi = lo + seg, e1 = b0 + len;
    if (hi > e1) hi = e1;
    for (int idx = lo + (int)threadIdx.x; idx < hi; idx += 512) {
        unsigned p = pairs[idx];
        int s = p & 524287u;
        int dl = p >> 19;
        atomicAdd(&t[dl], SUN[s].x);
    }
    __syncthreads();
    float* sb = slab + (size_t)blockIdx.x * BSZ;
    for (int j = threadIdx.x; j < BSZ; j += 512) sb[j] = t[j];
}

// ---------------- fused: merge SSU + f64 moments of (u,n,su,sn,ssu) ------------
__global__ __launch_bounds__(256) void m3mom(
    const float* __restrict__ slab, const float2* __restrict__ UN2,
    const float2* __restrict__ SUN, float* __restrict__ SSU,
    double* __restrict__ dm)
{
    int i = blockIdx.x * 256 + threadIdx.x;
    double z[5] = {0, 0, 0, 0, 0};
    if (i < NN) {
        int B = i >> BSH, low = i & (BSZ - 1);
        float ssu = 0.f;
#pragma unroll
        for (int m = 0; m < M; m++) ssu += slab[(size_t)(B * M + m) * BSZ + low];
        SSU[i] = ssu;
        float2 un = UN2[i]; float2 ss = SUN[i];
        z[0] = (double)un.x; z[1] = (double)un.y; z[2] = (double)ss.x;
        z[3] = (double)ss.y; z[4] = (double)ssu;
    }
    double m[20];
#pragma unroll
    for (int a = 0; a < 5; a++) m[a] = z[a];
    int idx = 5;
#pragma unroll
    for (int a = 0; a < 5; a++)
#pragma unroll
        for (int b = a; b < 5; b++) m[idx++] = z[a] * z[b];

    __shared__ double part[4][20];
    int lane = threadIdx.x & 63, wid = threadIdx.x >> 6;
#pragma unroll
    for (int k = 0; k < 20; k++) {
        double r = waveReduceD(m[k]);
        if (lane == 0) part[wid][k] = r;
    }
    __syncthreads();
    if (threadIdx.x < 20)
        atomicAdd(&dm[threadIdx.x],
                  part[0][threadIdx.x] + part[1][threadIdx.x] +
                  part[2][threadIdx.x] + part[3][threadIdx.x]);
}

// ---------------- K: fold weights + moments into the 4x6 logit matrix ----------
__device__ void mm1010(const float* in, const float* Wa, const float* Wb, float* out)
{
    float t[10];
    for (int m = 0; m < 10; m++) {
        float acc = 0.f;
        for (int k = 0; k < 10; k++) acc += in[k] * Wa[k * 10 + m];
        t[m] = acc;
    }
    for (int j = 0; j < 10; j++) {
        float acc = 0.f;
        for (int m = 0; m < 10; m++) acc += t[m] * Wb[m * 10 + j];
        out[j] = acc;
    }
}

__global__ void constk(
    const float* __restrict__ W1a, const float* __restrict__ b1a,
    const float* __restrict__ W1b, const float* __restrict__ b1b,
    const float* __restrict__ g1, const float* __restrict__ be1,
    const float* __restrict__ W2a, const float* __restrict__ b2a,
    const float* __restrict__ W2b, const float* __restrict__ b2b,
    const float* __restrict__ g2, const float* __restrict__ be2,
    const float* __restrict__ W3a, const float* __restrict__ b3a,
    const float* __restrict__ W3b, const float* __restrict__ b3b,
    const float* __restrict__ g3, const float* __restrict__ be3,
    const float* __restrict__ Wf, const float* __restrict__ bf_,
    const double* __restrict__ dm, float* __restrict__ Lout)
{
    if (threadIdx.x != 0 || blockIdx.x != 0) return;
    const double invN = 1.0 / (double)NN;
    double E[5];
    for (int m = 0; m < 5; m++) E[m] = dm[m] * invN;
    double C[5][5];
    {
        int idx = 5;
        for (int a = 0; a < 5; a++)
            for (int b = a; b < 5; b++) {
                double c = dm[idx++] * invN - E[a] * E[b];
                C[a][b] = c; C[b][a] = c;
            }
    }
    float v[10], c1[10];
    for (int j = 0; j < 10; j++) {
        float av = 0.f, ac = 0.f;
        for (int k = 0; k < 10; k++) {
            av += W1a[k] * W1b[k * 10 + j];
            ac += b1a[k] * W1b[k * 10 + j];
        }
        v[j] = av; c1[j] = ac + b1b[j];
    }
    double Eu = E[0], Vu = C[0][0];
    float p[10], q[10];
    for (int j = 0; j < 10; j++) {
        float var1 = (float)(Vu * (double)v[j] * (double)v[j]);
        float sc1 = g1[j] * rsqrtf(var1 + BN_EPS);
        p[j] = sc1 * v[j];
        q[j] = be1[j] - (float)Eu * p[j];
    }
    float r[10], s[10], d2[10];
    mm1010(p, W2a, W2b, r);
    mm1010(q, W2a, W2b, s);
    for (int j = 0; j < 10; j++) {
        float acc = b2b[j];
        for (int m = 0; m < 10; m++) acc += b2a[m] * W2b[m * 10 + j];
        d2[j] = acc;
    }
    double Ea = E[0] + E[2], Eb = 1.0 + E[1];
    double Va = C[0][0] + 2.0 * C[0][2] + C[2][2];
    double Vb = C[1][1];
    double Cab = C[0][1] + C[2][1];
    float rt[10], st[10], dt[10];
    for (int j = 0; j < 10; j++) {
        double rj = r[j], sj = s[j];
        float var2 = (float)(Va * rj * rj + Vb * sj * sj + 2.0 * Cab * rj * sj);
        float sc2 = g2[j] * rsqrtf(var2 + BN_EPS);
        rt[j] = sc2 * r[j];
        st[j] = sc2 * s[j];
        dt[j] = be2[j] - sc2 * (float)(Ea * rj + Eb * sj);
    }
    float r3[10], s3[10], t3[10], d3[10];
    mm1010(rt, W3a, W3b, r3);
    mm1010(st, W3a, W3b, s3);
    mm1010(dt, W3a, W3b, t3);
    for (int j = 0; j < 10; j++) {
        float acc = b3b[j];
        for (int m = 0; m < 10; m++) acc += b3a[m] * W3b[m * 10 + j];
        d3[j] = acc;
    }
    const double gA[5] = {1, 0, 2, 0, 1};
    const double gB[5] = {0, 2, 0, 1, 0};
    const double gC[5] = {0, 1, 0, 0, 0};
    double EA = E[0] + 2.0 * E[2] + E[4];
    double EB = 1.0 + 2.0 * E[1] + E[3];
    double EC = 1.0 + E[1];
    double VA = 0, VB = 0, VC = 0, CAB = 0, CAC = 0, CBC = 0;
    for (int a = 0; a < 5; a++)
        for (int b = 0; b < 5; b++) {
            double c = C[a][b];
            VA  += gA[a] * gA[b] * c;
            VB  += gB[a] * gB[b] * c;
            VC  += gC[a] * gC[b] * c;
            CAB += gA[a] * gB[b] * c;
            CAC += gA[a] * gC[b] * c;
            CBC += gB[a] * gC[b] * c;
        }
    float rh[10], sh[10], th[10], dh[10];
    for (int j = 0; j < 10; j++) {
        double rj = r3[j], sj = s3[j], tj = t3[j];
        float var3 = (float)(VA * rj * rj + VB * sj * sj + VC * tj * tj
                             + 2.0 * (CAB * rj * sj + CAC * rj * tj + CBC * sj * tj));
        float sc3 = g3[j] * rsqrtf(var3 + BN_EPS);
        rh[j] = sc3 * r3[j];
        sh[j] = sc3 * s3[j];
        th[j] = sc3 * t3[j];
        dh[j] = be3[j] - sc3 * (float)(EA * rj + EB * sj + EC * tj);
    }
    for (int k = 0; k < 4; k++) {
        float Lu = 0, Ln = 0, Lsu = 0, Lsn = 0, Lssu = 0, L0 = bf_[k];
        for (int j = 0; j < 10; j++) {
            float wf1 = Wf[j * 4 + k];
            float wf2 = Wf[(10 + j) * 4 + k];
            float wf3 = Wf[(20 + j) * 4 + k];
            Lu   += p[j] * wf1 + rt[j] * wf2 + rh[j] * wf3;
            Ln   += st[j] * wf2 + (2.f * sh[j] + th[j]) * wf3;
            Lsu  += rt[j] * wf2 + 2.f * rh[j] * wf3;
            Lsn  += sh[j] * wf3;
            Lssu += rh[j] * wf3;
            L0   += q[j] * wf1 + (st[j] + dt[j]) * wf2 + (sh[j] + th[j] + dh[j]) * wf3;
        }
        Lout[0 * 4 + k] = Lu;  Lout[1 * 4 + k] = Ln;   Lout[2 * 4 + k] = Lsu;
        Lout[3 * 4 + k] = Lsn; Lout[4 * 4 + k] = Lssu; Lout[5 * 4 + k] = L0;
    }
}

// ---------------- F: logits -> softmax -> s (f32 out + bf16 side table) --------
__global__ __launch_bounds__(256) void finalk(
    const float2* __restrict__ UN2, const float2* __restrict__ SUN,
    const float* __restrict__ SSU, const float* __restrict__ L,
    float4* __restrict__ sout, ushort4* __restrict__ sbf)
{
    __shared__ float sL[24];
    if (threadIdx.x < 24) sL[threadIdx.x] = L[threadIdx.x];
    __syncthreads();
    int i = blockIdx.x * 256 + threadIdx.x;
    if (i >= NN) return;
    float2 un = UN2[i]; float2 ss = SUN[i];
    float u = un.x, n = un.y, su = ss.x, sn = ss.y, ssu = SSU[i];
    float lg[4];
#pragma unroll
    for (int k = 0; k < 4; k++)
        lg[k] = sL[k] * u + sL[4 + k] * n + sL[8 + k] * su
              + sL[12 + k] * sn + sL[16 + k] * ssu + sL[20 + k];
    float mx = fmaxf(fmaxf(lg[0], lg[1]), fmaxf(lg[2], lg[3]));
    float e0 = __expf(lg[0] - mx), e1 = __expf(lg[1] - mx);
    float e2 = __expf(lg[2] - mx), e3 = __expf(lg[3] - mx);
    float inv = 1.f / (e0 + e1 + e2 + e3);
    float s0 = e0 * inv, s1 = e1 * inv, s2 = e2 * inv, s3 = e3 * inv;
    sout[i] = make_float4(s0, s1, s2, s3);
    ushort4 pk; pk.x = f2u(s0); pk.y = f2u(s1); pk.z = f2u(s2); pk.w = f2u(s3);
    sbf[i] = pk;
}

// ---------------- modk over buckets: two_m, pos, ds (bf16 gathers) -------------
__global__ __launch_bounds__(512) void modk(
    const unsigned* __restrict__ pairs, const unsigned short* __restrict__ wp,
    const int* __restrict__ base, const int* __restrict__ cnt,
    const ushort4* __restrict__ sbf, float* __restrict__ scal)
{
    int B = blockIdx.x / M, sl = blockIdx.x % M;
    int b0 = base[B], len = cnt[B];
    int seg = (len + M - 1) / M;
    int lo = b0 + sl * seg;
    int hi = lo + seg, e1 = b0 + len;
    if (hi > e1) hi = e1;
    float acc[6] = {0, 0, 0, 0, 0, 0};
    for (int idx = lo + (int)threadIdx.x; idx < hi; idx += 512) {
        unsigned p = pairs[idx];
        int s = p & 524287u;
        int d = (B << BSH) + (int)(p >> 19);
        float we = u2f(wp[idx]);
        ushort4 ua = sbf[s];
        ushort4 ub = sbf[d];
        float ax = u2f(ua.x), ay = u2f(ua.y), az = u2f(ua.z), aw = u2f(ua.w);
        float bx = u2f(ub.x), by = u2f(ub.y), bz = u2f(ub.z), bw = u2f(ub.w);
        acc[0] += we;
        acc[1] += we * (ax * bx + ay * by + az * bz + aw * bw);
        acc[2] += we * ax; acc[3] += we * ay;
        acc[4] += we * az; acc[5] += we * aw;
    }
    __shared__ float part[8][6];
    int lane = threadIdx.x & 63, wid = threadIdx.x >> 6;
#pragma unroll
    for (int k = 0; k < 6; k++) {
        float r = waveReduceF(acc[k]);
        if (lane == 0) part[wid][k] = r;
    }
    __syncthreads();
    if (threadIdx.x < 6) {
        float vsum = 0.f;
#pragma unroll
        for (int wdi = 0; wdi < 8; wdi++) vsum += part[wdi][threadIdx.x];
        int off = (threadIdx.x == 0) ? 128 : (threadIdx.x == 1 ? 129 : 130 + threadIdx.x);
        atomicAdd(&scal[off], vsum);
    }
}

// ---------------- q ------------------------------------------------------------
__global__ void qk(const float* __restrict__ scal, float* __restrict__ out)
{
    if (threadIdx.x == 0) {
        float inv = 1.f / scal[128];
        float posv = scal[129] * inv;
        float acc = 0.f;
#pragma unroll
        for (int k = 0; k < 4; k++) {
            float d = scal[132 + k] * inv;
            acc += d * d;
        }
        out[(size_t)NN * 4] = posv - acc;
    }
}

extern "C" void kernel_launch(void* const* d_in, const int* in_sizes, int n_in,
                              void* d_out, int out_size, void* d_ws, size_t ws_size,
                              hipStream_t stream) {
    const float* x  = (const float*)d_in[0];
    const int*  ei  = (const int*)d_in[1];
    const int*  src = ei;
    const int*  dst = ei + NE;
    const float* w   = (const float*)d_in[2];
    const float* W1a = (const float*)d_in[3];  const float* b1a = (const float*)d_in[4];
    const float* W1b = (const float*)d_in[5];  const float* b1b = (const float*)d_in[6];
    const float* g1  = (const float*)d_in[7];  const float* be1 = (const float*)d_in[8];
    const float* W2a = (const float*)d_in[9];  const float* b2a = (const float*)d_in[10];
    const float* W2b = (const float*)d_in[11]; const float* b2b = (const float*)d_in[12];
    const float* g2  = (const float*)d_in[13]; const float* be2 = (const float*)d_in[14];
    const float* W3a = (const float*)d_in[15]; const float* b3a = (const float*)d_in[16];
    const float* W3b = (const float*)d_in[17]; const float* b3b = (const float*)d_in[18];
    const float* g3  = (const float*)d_in[19]; const float* be3 = (const float*)d_in[20];
    const float* Wf  = (const float*)d_in[21]; const float* bfb = (const float*)d_in[22];

    // workspace layout:
    //  floats sc[0..1023]: two_m@128, pos@129, ds@132..135, L@160..183,
    //    dm (20 doubles) @ float-idx 384 (byte 1536),
    //    count ints @ sci[576], base @ sci[704], cur @ sci[832]
    //  byte 4096: pairs uint[NE] (32MB) | wp ushort[NE] (16MB) |
    //    slab float[NAGG*2*BSZ] (32.25MB) | UN2 float2[NN] | SUN float2[NN] |
    //    SSU float[NN] | sbf ushort4[NN]
    float*  sc   = (float*)d_ws;
    int*    sci  = (int*)d_ws;
    double* dm   = (double*)(sc + 384);
    unsigned* pairs = (unsigned*)(sc + 1024);
    unsigned short* wp = (unsigned short*)(pairs + NE);
    float*  slab = (float*)(wp + NE);
    float2* UN2  = (float2*)(slab + (size_t)NAGG * 2 * BSZ);
    float2* SUN  = UN2 + NN;
    float*  SSU  = (float*)(SUN + NN);
    ushort4* sbf = (ushort4*)(SSU + NN);
    float*  sout = (float*)d_out;

    const int NB_N  = (NN + 255) / 256;
    const int NB_EQ = (NE / 4 + 1023) / 1024;   // 1954 blocks over int4-quads

    hipMemsetAsync(sc, 0, 4096, stream);

    // bucketize once (dst -> 123 buckets of 4096 nodes), block counting sort
    countk<<<NB_EQ, 512, 0, stream>>>((const int4*)dst, sci + 576);
    scank<<<1, 64, 0, stream>>>(sci + 576, sci + 704, sci + 832);
    scatterk<<<NB_EQ, 512, 0, stream>>>((const int4*)src, (const int4*)dst,
                                        (const float4*)w, sci + 832, pairs, wp);

    // three aggregation rounds via LDS privatization (no global atomics)
    agg1k<<<NAGG, 512, 32768, stream>>>(pairs, sci + 704, sci + 576, x, slab);
    mergeN1<<<NB_N, 256, 0, stream>>>(slab, x, UN2);
    agg2k<<<NAGG, 512, 32768, stream>>>(pairs, sci + 704, sci + 576, UN2, slab);
    mergeN2<<<NB_N, 256, 0, stream>>>(slab, SUN);
    agg3k<<<NAGG, 512, 16384, stream>>>(pairs, sci + 704, sci + 576, SUN, slab);
    m3mom<<<NB_N, 256, 0, stream>>>(slab, UN2, SUN, SSU, dm);

    // closed-form logit matrix -> softmax -> modularity
    constk<<<1, 64, 0, stream>>>(W1a, b1a, W1b, b1b, g1, be1,
                                 W2a, b2a, W2b, b2b, g2, be2,
                                 W3a, b3a, W3b, b3b, g3, be3,
                                 Wf, bfb, dm, sc + 160);
    finalk<<<NB_N, 256, 0, stream>>>(UN2, SUN, SSU, sc + 160, (float4*)sout, sbf);
    modk<<<NAGG, 512, 0, stream>>>(pairs, wp, sci + 704, sci + 576, sbf, sc);
    qk<<<1, 64, 0, stream>>>(sc, sout);
}

// Round 9
// 590.489 us; speedup vs baseline: 15.8285x; 1.0864x over previous
//
#include <hip/hip_runtime.h>
#include <hip/hip_bf16.h>

#define NN 500000
#define NE 8000000
#define NB 123           // buckets of 4096 nodes: 123*4096 = 503808 >= NN
#define BSH 12
#define BSZ 4096
#define CAP 69632        // fixed bucket capacity (65536 mean + 16 sigma), mult of 4
#define M 8              // slices (blocks) per bucket
#define NAGG (NB * M)    // 984 blocks
#define BN_EPS 1e-5f

__device__ __forceinline__ float waveReduceF(float v) {
#pragma unroll
    for (int o = 32; o > 0; o >>= 1) v += __shfl_down(v, o, 64);
    return v;
}
__device__ __forceinline__ double waveReduceD(double v) {
#pragma unroll
    for (int o = 32; o > 0; o >>= 1) v += __shfl_down(v, o, 64);
    return v;
}
__device__ __forceinline__ float u2f(unsigned short u) {
    return __bfloat162float(__builtin_bit_cast(__hip_bfloat16, u));
}
__device__ __forceinline__ unsigned short f2u(float f) {
    return __builtin_bit_cast(unsigned short, __float2bfloat16(f));
}

// ---------------- init cursors: cur[b] = b*CAP ---------------------------------
__global__ void initk(int* __restrict__ cur)
{
    if (threadIdx.x < NB) cur[threadIdx.x] = (int)threadIdx.x * CAP;
}

// ---------------- bucketize: block counting sort, coalesced emit ---------------
__global__ __launch_bounds__(512) void scatterk(
    const int4* __restrict__ src4, const int4* __restrict__ dst4,
    const float4* __restrict__ w4, int* __restrict__ cur,
    unsigned* __restrict__ pairs, unsigned short* __restrict__ wp)
{
    __shared__ unsigned sEnt[4096];        // 16 KB
    __shared__ unsigned short sW[4096];    // 8 KB
    __shared__ unsigned char sB[4096];     // 4 KB
    __shared__ int h[8][128];              // per-wave histograms
    __shared__ int wOff[8][128];           // cross-wave prefix per bucket
    __shared__ int bOff[128];              // block-local bucket prefix
    __shared__ int lb[128];                // global base for this block per bucket
    __shared__ int tot[128];

    int tid = threadIdx.x, wv = tid >> 6;
    for (int j = tid; j < 8 * 128; j += 512) (&h[0][0])[j] = 0;
    __syncthreads();

    unsigned en[8]; unsigned short wb[8]; int rb[8];   // rk<<8 | b, or -1
#pragma unroll
    for (int k = 0; k < 2; k++) {
        int q = blockIdx.x * 1024 + k * 512 + tid;
        if (q < NE / 4) {
            int4 s4 = src4[q]; int4 d4 = dst4[q]; float4 ww = w4[q];
            int ss[4] = {s4.x, s4.y, s4.z, s4.w};
            int dd[4] = {d4.x, d4.y, d4.z, d4.w};
            float fw[4] = {ww.x, ww.y, ww.z, ww.w};
#pragma unroll
            for (int i = 0; i < 4; i++) {
                int d = dd[i], b = d >> BSH;
                en[k * 4 + i] = ((unsigned)(d & (BSZ - 1)) << 19) | (unsigned)ss[i];
                wb[k * 4 + i] = f2u(fw[i]);
                int rk = atomicAdd(&h[wv][b], 1);
                rb[k * 4 + i] = (rk << 8) | b;
            }
        } else {
#pragma unroll
            for (int i = 0; i < 4; i++) rb[k * 4 + i] = -1;
        }
    }
    __syncthreads();
    if (tid < NB) {
        int acc = 0;
#pragma unroll
        for (int w = 0; w < 8; w++) { wOff[w][tid] = acc; acc += h[w][tid]; }
        tot[tid] = acc;
        lb[tid] = atomicAdd(&cur[tid], acc);
    }
    __syncthreads();
    if (tid == 0) {
        int acc = 0;
        for (int b = 0; b < NB; b++) { bOff[b] = acc; acc += tot[b]; }
    }
    __syncthreads();
#pragma unroll
    for (int k = 0; k < 8; k++) {
        if (rb[k] >= 0) {
            int b = rb[k] & 255, rk = rb[k] >> 8;
            int pos = bOff[b] + wOff[wv][b] + rk;
            sEnt[pos] = en[k]; sW[pos] = wb[k]; sB[pos] = (unsigned char)b;
        }
    }
    __syncthreads();
    int nE = NE - blockIdx.x * 4096; if (nE > 4096) nE = 4096;
    for (int j = tid; j < nE; j += 512) {
        int b = sB[j];
        int glob = lb[b] + (j - bOff[b]);
        pairs[glob] = sEnt[j];
        wp[glob] = sW[j];
    }
}

// ---------------- agg pass 1: LDS tables (sum x, count), 4-wide ILP ------------
__global__ __launch_bounds__(512) void agg1k(
    const unsigned* __restrict__ pairs, const int* __restrict__ cur,
    const float* __restrict__ x, float* __restrict__ slab)
{
    extern __shared__ float t[];   // [0..BSZ)=sum x, [BSZ..2BSZ)=count
    for (int j = threadIdx.x; j < 2 * BSZ; j += 512) t[j] = 0.f;
    __syncthreads();
    int B = blockIdx.x / M, sl = blockIdx.x % M;
    int b0 = B * CAP;
    int len = cur[B] - b0;
    int seg = (((len + M - 1) / M) + 3) & ~3;
    int lo = b0 + sl * seg;
    int hi = lo + seg, e1 = b0 + len;
    if (hi > e1) hi = e1;
    int n = hi - lo;
    if (n > 0) {
        int nq = n >> 2;
        const uint4* pq = (const uint4*)(pairs + lo);
        for (int i = threadIdx.x; i < nq; i += 512) {
            uint4 p = pq[i];
            float x0 = x[p.x & 524287u];
            float x1 = x[p.y & 524287u];
            float x2 = x[p.z & 524287u];
            float x3 = x[p.w & 524287u];
            atomicAdd(&t[p.x >> 19], x0); atomicAdd(&t[BSZ + (p.x >> 19)], 1.f);
            atomicAdd(&t[p.y >> 19], x1); atomicAdd(&t[BSZ + (p.y >> 19)], 1.f);
            atomicAdd(&t[p.z >> 19], x2); atomicAdd(&t[BSZ + (p.z >> 19)], 1.f);
            atomicAdd(&t[p.w >> 19], x3); atomicAdd(&t[BSZ + (p.w >> 19)], 1.f);
        }
        int rem = n & 3;
        if ((int)threadIdx.x < rem) {
            unsigned p = pairs[lo + (nq << 2) + threadIdx.x];
            atomicAdd(&t[p >> 19], x[p & 524287u]);
            atomicAdd(&t[BSZ + (p >> 19)], 1.f);
        }
    }
    __syncthreads();
    float* sb = slab + (size_t)blockIdx.x * (2 * BSZ);
    for (int j = threadIdx.x; j < 2 * BSZ; j += 512) sb[j] = t[j];
}

__global__ __launch_bounds__(256) void mergeN1(
    const float* __restrict__ slab, const float* __restrict__ x,
    float2* __restrict__ UN2)
{
    int i = blockIdx.x * 256 + threadIdx.x;
    if (i >= NN) return;
    int B = i >> BSH, low = i & (BSZ - 1);
    float sx = 0.f, cn = 0.f;
#pragma unroll
    for (int m = 0; m < M; m++) {
        const float* sb = slab + (size_t)(B * M + m) * (2 * BSZ);
        sx += sb[low];
        cn += sb[BSZ + low];
    }
    UN2[i] = make_float2(x[i] + sx, cn);
}

// ---------------- agg pass 2: LDS tables (sum u, sum n), 4-wide ILP ------------
__global__ __launch_bounds__(512) void agg2k(
    const unsigned* __restrict__ pairs, const int* __restrict__ cur,
    const float2* __restrict__ UN2, float* __restrict__ slab)
{
    extern __shared__ float t[];
    for (int j = threadIdx.x; j < 2 * BSZ; j += 512) t[j] = 0.f;
    __syncthreads();
    int B = blockIdx.x / M, sl = blockIdx.x % M;
    int b0 = B * CAP;
    int len = cur[B] - b0;
    int seg = (((len + M - 1) / M) + 3) & ~3;
    int lo = b0 + sl * seg;
    int hi = lo + seg, e1 = b0 + len;
    if (hi > e1) hi = e1;
    int n = hi - lo;
    if (n > 0) {
        int nq = n >> 2;
        const uint4* pq = (const uint4*)(pairs + lo);
        for (int i = threadIdx.x; i < nq; i += 512) {
            uint4 p = pq[i];
            float2 v0 = UN2[p.x & 524287u];
            float2 v1 = UN2[p.y & 524287u];
            float2 v2 = UN2[p.z & 524287u];
            float2 v3 = UN2[p.w & 524287u];
            atomicAdd(&t[p.x >> 19], v0.x); atomicAdd(&t[BSZ + (p.x >> 19)], v0.y);
            atomicAdd(&t[p.y >> 19], v1.x); atomicAdd(&t[BSZ + (p.y >> 19)], v1.y);
            atomicAdd(&t[p.z >> 19], v2.x); atomicAdd(&t[BSZ + (p.z >> 19)], v2.y);
            atomicAdd(&t[p.w >> 19], v3.x); atomicAdd(&t[BSZ + (p.w >> 19)], v3.y);
        }
        int rem = n & 3;
        if ((int)threadIdx.x < rem) {
            unsigned p = pairs[lo + (nq << 2) + threadIdx.x];
            float2 v = UN2[p & 524287u];
            atomicAdd(&t[p >> 19], v.x);
            atomicAdd(&t[BSZ + (p >> 19)], v.y);
        }
    }
    __syncthreads();
    float* sb = slab + (size_t)blockIdx.x * (2 * BSZ);
    for (int j = threadIdx.x; j < 2 * BSZ; j += 512) sb[j] = t[j];
}

__global__ __launch_bounds__(256) void mergeN2(
    const float* __restrict__ slab, float2* __restrict__ SUN)
{
    int i = blockIdx.x * 256 + threadIdx.x;
    if (i >= NN) return;
    int B = i >> BSH, low = i & (BSZ - 1);
    float su = 0.f, sn = 0.f;
#pragma unroll
    for (int m = 0; m < M; m++) {
        const float* sb = slab + (size_t)(B * M + m) * (2 * BSZ);
        su += sb[low];
        sn += sb[BSZ + low];
    }
    SUN[i] = make_float2(su, sn);
}

// ---------------- agg pass 3: LDS table (sum su), 4-wide ILP -------------------
__global__ __launch_bounds__(512) void agg3k(
    const unsigned* __restrict__ pairs, const int* __restrict__ cur,
    const float2* __restrict__ SUN, float* __restrict__ slab)
{
    extern __shared__ float t[];   // [0..BSZ)
    for (int j = threadIdx.x; j < BSZ; j += 512) t[j] = 0.f;
    __syncthreads();
    int B = blockIdx.x / M, sl = blockIdx.x % M;
    int b0 = B * CAP;
    int len = cur[B] - b0;
    int seg = (((len + M - 1) / M) + 3) & ~3;
    int lo = b0 + sl * seg;
    int hi = lo + seg, e1 = b0 + len;
    if (hi > e1) hi = e1;
    int n = hi - lo;
    if (n > 0) {
        int nq = n >> 2;
        const uint4* pq = (const uint4*)(pairs + lo);
        for (int i = threadIdx.x; i < nq; i += 512) {
            uint4 p = pq[i];
            float v0 = SUN[p.x & 524287u].x;
            float v1 = SUN[p.y & 524287u].x;
            float v2 = SUN[p.z & 524287u].x;
            float v3 = SUN[p.w & 524287u].x;
            atomicAdd(&t[p.x >> 19], v0);
            atomicAdd(&t[p.y >> 19], v1);
            atomicAdd(&t[p.z >> 19], v2);
            atomicAdd(&t[p.w >> 19], v3);
        }
        int rem = n & 3;
        if ((int)threadIdx.x < rem) {
            unsigned p = pairs[lo + (nq << 2) + threadIdx.x];
            atomicAdd(&t[p >> 19], SUN[p & 524287u].x);
        }
    }
    __syncthreads();
    float* sb = slab + (size_t)blockIdx.x * BSZ;
    for (int j = threadIdx.x; j < BSZ; j += 512) sb[j] = t[j];
}

// ---------------- fused: merge SSU + f64 moments of (u,n,su,sn,ssu) ------------
__global__ __launch_bounds__(256) void m3mom(
    const float* __restrict__ slab, const float2* __restrict__ UN2,
    const float2* __restrict__ SUN, float* __restrict__ SSU,
    double* __restrict__ dm)
{
    int i = blockIdx.x * 256 + threadIdx.x;
    double z[5] = {0, 0, 0, 0, 0};
    if (i < NN) {
        int B = i >> BSH, low = i & (BSZ - 1);
        float ssu = 0.f;
#pragma unroll
        for (int m = 0; m < M; m++) ssu += slab[(size_t)(B * M + m) * BSZ + low];
        SSU[i] = ssu;
        float2 un = UN2[i]; float2 ss = SUN[i];
        z[0] = (double)un.x; z[1] = (double)un.y; z[2] = (double)ss.x;
        z[3] = (double)ss.y; z[4] = (double)ssu;
    }
    double m[20];
#pragma unroll
    for (int a = 0; a < 5; a++) m[a] = z[a];
    int idx = 5;
#pragma unroll
    for (int a = 0; a < 5; a++)
#pragma unroll
        for (int b = a; b < 5; b++) m[idx++] = z[a] * z[b];

    __shared__ double part[4][20];
    int lane = threadIdx.x & 63, wid = threadIdx.x >> 6;
#pragma unroll
    for (int k = 0; k < 20; k++) {
        double r = waveReduceD(m[k]);
        if (lane == 0) part[wid][k] = r;
    }
    __syncthreads();
    if (threadIdx.x < 20)
        atomicAdd(&dm[threadIdx.x],
                  part[0][threadIdx.x] + part[1][threadIdx.x] +
                  part[2][threadIdx.x] + part[3][threadIdx.x]);
}

// ---------------- K: fold weights + moments into the 4x6 logit matrix ----------
__device__ void mm1010(const float* in, const float* Wa, const float* Wb, float* out)
{
    float t[10];
    for (int m = 0; m < 10; m++) {
        float acc = 0.f;
        for (int k = 0; k < 10; k++) acc += in[k] * Wa[k * 10 + m];
        t[m] = acc;
    }
    for (int j = 0; j < 10; j++) {
        float acc = 0.f;
        for (int m = 0; m < 10; m++) acc += t[m] * Wb[m * 10 + j];
        out[j] = acc;
    }
}

__global__ void constk(
    const float* __restrict__ W1a, const float* __restrict__ b1a,
    const float* __restrict__ W1b, const float* __restrict__ b1b,
    const float* __restrict__ g1, const float* __restrict__ be1,
    const float* __restrict__ W2a, const float* __restrict__ b2a,
    const float* __restrict__ W2b, const float* __restrict__ b2b,
    const float* __restrict__ g2, const float* __restrict__ be2,
    const float* __restrict__ W3a, const float* __restrict__ b3a,
    const float* __restrict__ W3b, const float* __restrict__ b3b,
    const float* __restrict__ g3, const float* __restrict__ be3,
    const float* __restrict__ Wf, const float* __restrict__ bf_,
    const double* __restrict__ dm, float* __restrict__ Lout)
{
    if (threadIdx.x != 0 || blockIdx.x != 0) return;
    const double invN = 1.0 / (double)NN;
    double E[5];
    for (int m = 0; m < 5; m++) E[m] = dm[m] * invN;
    double C[5][5];
    {
        int idx = 5;
        for (int a = 0; a < 5; a++)
            for (int b = a; b < 5; b++) {
                double c = dm[idx++] * invN - E[a] * E[b];
                C[a][b] = c; C[b][a] = c;
            }
    }
    float v[10], c1[10];
    for (int j = 0; j < 10; j++) {
        float av = 0.f, ac = 0.f;
        for (int k = 0; k < 10; k++) {
            av += W1a[k] * W1b[k * 10 + j];
            ac += b1a[k] * W1b[k * 10 + j];
        }
        v[j] = av; c1[j] = ac + b1b[j];
    }
    double Eu = E[0], Vu = C[0][0];
    float p[10], q[10];
    for (int j = 0; j < 10; j++) {
        float var1 = (float)(Vu * (double)v[j] * (double)v[j]);
        float sc1 = g1[j] * rsqrtf(var1 + BN_EPS);
        p[j] = sc1 * v[j];
        q[j] = be1[j] - (float)Eu * p[j];
    }
    float r[10], s[10], d2[10];
    mm1010(p, W2a, W2b, r);
    mm1010(q, W2a, W2b, s);
    for (int j = 0; j < 10; j++) {
        float acc = b2b[j];
        for (int m = 0; m < 10; m++) acc += b2a[m] * W2b[m * 10 + j];
        d2[j] = acc;
    }
    double Ea = E[0] + E[2], Eb = 1.0 + E[1];
    double Va = C[0][0] + 2.0 * C[0][2] + C[2][2];
    double Vb = C[1][1];
    double Cab = C[0][1] + C[2][1];
    float rt[10], st[10], dt[10];
    for (int j = 0; j < 10; j++) {
        double rj = r[j], sj = s[j];
        float var2 = (float)(Va * rj * rj + Vb * sj * sj + 2.0 * Cab * rj * sj);
        float sc2 = g2[j] * rsqrtf(var2 + BN_EPS);
        rt[j] = sc2 * r[j];
        st[j] = sc2 * s[j];
        dt[j] = be2[j] - sc2 * (float)(Ea * rj + Eb * sj);
    }
    float r3[10], s3[10], t3[10], d3[10];
    mm1010(rt, W3a, W3b, r3);
    mm1010(st, W3a, W3b, s3);
    mm1010(dt, W3a, W3b, t3);
    for (int j = 0; j < 10; j++) {
        float acc = b3b[j];
        for (int m = 0; m < 10; m++) acc += b3a[m] * W3b[m * 10 + j];
        d3[j] = acc;
    }
    const double gA[5] = {1, 0, 2, 0, 1};
    const double gB[5] = {0, 2, 0, 1, 0};
    const double gC[5] = {0, 1, 0, 0, 0};
    double EA = E[0] + 2.0 * E[2] + E[4];
    double EB = 1.0 + 2.0 * E[1] + E[3];
    double EC = 1.0 + E[1];
    double VA = 0, VB = 0, VC = 0, CAB = 0, CAC = 0, CBC = 0;
    for (int a = 0; a < 5; a++)
        for (int b = 0; b < 5; b++) {
            double c = C[a][b];
            VA  += gA[a] * gA[b] * c;
            VB  += gB[a] * gB[b] * c;
            VC  += gC[a] * gC[b] * c;
            CAB += gA[a] * gB[b] * c;
            CAC += gA[a] * gC[b] * c;
            CBC += gB[a] * gC[b] * c;
        }
    float rh[10], sh[10], th[10], dh[10];
    for (int j = 0; j < 10; j++) {
        double rj = r3[j], sj = s3[j], tj = t3[j];
        float var3 = (float)(VA * rj * rj + VB * sj * sj + VC * tj * tj
                             + 2.0 * (CAB * rj * sj + CAC * rj * tj + CBC * sj * tj));
        float sc3 = g3[j] * rsqrtf(var3 + BN_EPS);
        rh[j] = sc3 * r3[j];
        sh[j] = sc3 * s3[j];
        th[j] = sc3 * t3[j];
        dh[j] = be3[j] - sc3 * (float)(EA * rj + EB * sj + EC * tj);
    }
    for (int k = 0; k < 4; k++) {
        float Lu = 0, Ln = 0, Lsu = 0, Lsn = 0, Lssu = 0, L0 = bf_[k];
        for (int j = 0; j < 10; j++) {
            float wf1 = Wf[j * 4 + k];
            float wf2 = Wf[(10 + j) * 4 + k];
            float wf3 = Wf[(20 + j) * 4 + k];
            Lu   += p[j] * wf1 + rt[j] * wf2 + rh[j] * wf3;
            Ln   += st[j] * wf2 + (2.f * sh[j] + th[j]) * wf3;
            Lsu  += rt[j] * wf2 + 2.f * rh[j] * wf3;
            Lsn  += sh[j] * wf3;
            Lssu += rh[j] * wf3;
            L0   += q[j] * wf1 + (st[j] + dt[j]) * wf2 + (sh[j] + th[j] + dh[j]) * wf3;
        }
        Lout[0 * 4 + k] = Lu;  Lout[1 * 4 + k] = Ln;   Lout[2 * 4 + k] = Lsu;
        Lout[3 * 4 + k] = Lsn; Lout[4 * 4 + k] = Lssu; Lout[5 * 4 + k] = L0;
    }
}

// ---------------- F: logits -> softmax -> s (f32 out + bf16 side table) --------
__global__ __launch_bounds__(256) void finalk(
    const float2* __restrict__ UN2, const float2* __restrict__ SUN,
    const float* __restrict__ SSU, const float* __restrict__ L,
    float4* __restrict__ sout, ushort4* __restrict__ sbf)
{
    __shared__ float sL[24];
    if (threadIdx.x < 24) sL[threadIdx.x] = L[threadIdx.x];
    __syncthreads();
    int i = blockIdx.x * 256 + threadIdx.x;
    if (i >= NN) return;
    float2 un = UN2[i]; float2 ss = SUN[i];
    float u = un.x, n = un.y, su = ss.x, sn = ss.y, ssu = SSU[i];
    float lg[4];
#pragma unroll
    for (int k = 0; k < 4; k++)
        lg[k] = sL[k] * u + sL[4 + k] * n + sL[8 + k] * su
              + sL[12 + k] * sn + sL[16 + k] * ssu + sL[20 + k];
    float mx = fmaxf(fmaxf(lg[0], lg[1]), fmaxf(lg[2], lg[3]));
    float e0 = __expf(lg[0] - mx), e1 = __expf(lg[1] - mx);
    float e2 = __expf(lg[2] - mx), e3 = __expf(lg[3] - mx);
    float inv = 1.f / (e0 + e1 + e2 + e3);
    float s0 = e0 * inv, s1 = e1 * inv, s2 = e2 * inv, s3 = e3 * inv;
    sout[i] = make_float4(s0, s1, s2, s3);
    ushort4 pk; pk.x = f2u(s0); pk.y = f2u(s1); pk.z = f2u(s2); pk.w = f2u(s3);
    sbf[i] = pk;
}

// ---------------- modk over buckets: two_m, pos, ds (bf16, 4-wide ILP) ---------
__global__ __launch_bounds__(512) void modk(
    const unsigned* __restrict__ pairs, const unsigned short* __restrict__ wp,
    const int* __restrict__ cur, const ushort4* __restrict__ sbf,
    float* __restrict__ scal)
{
    int B = blockIdx.x / M, sl = blockIdx.x % M;
    int b0 = B * CAP;
    int len = cur[B] - b0;
    int seg = (((len + M - 1) / M) + 3) & ~3;
    int lo = b0 + sl * seg;
    int hi = lo + seg, e1 = b0 + len;
    if (hi > e1) hi = e1;
    int n = hi - lo;
    float acc[6] = {0, 0, 0, 0, 0, 0};
    if (n > 0) {
        int nq = n >> 2;
        const uint4* pq = (const uint4*)(pairs + lo);
        const ushort4* wq = (const ushort4*)(wp + lo);
        for (int i = threadIdx.x; i < nq; i += 512) {
            uint4 p = pq[i];
            ushort4 w4v = wq[i];
            ushort4 ua0 = sbf[p.x & 524287u];
            ushort4 ua1 = sbf[p.y & 524287u];
            ushort4 ua2 = sbf[p.z & 524287u];
            ushort4 ua3 = sbf[p.w & 524287u];
            ushort4 ub0 = sbf[(B << BSH) + (int)(p.x >> 19)];
            ushort4 ub1 = sbf[(B << BSH) + (int)(p.y >> 19)];
            ushort4 ub2 = sbf[(B << BSH) + (int)(p.z >> 19)];
            ushort4 ub3 = sbf[(B << BSH) + (int)(p.w >> 19)];
            unsigned short ws[4] = {w4v.x, w4v.y, w4v.z, w4v.w};
            ushort4 uas[4] = {ua0, ua1, ua2, ua3};
            ushort4 ubs[4] = {ub0, ub1, ub2, ub3};
#pragma unroll
            for (int e = 0; e < 4; e++) {
                float we = u2f(ws[e]);
                float ax = u2f(uas[e].x), ay = u2f(uas[e].y);
                float az = u2f(uas[e].z), aw = u2f(uas[e].w);
                float bx = u2f(ubs[e].x), by = u2f(ubs[e].y);
                float bz = u2f(ubs[e].z), bw = u2f(ubs[e].w);
                acc[0] += we;
                acc[1] += we * (ax * bx + ay * by + az * bz + aw * bw);
                acc[2] += we * ax; acc[3] += we * ay;
                acc[4] += we * az; acc[5] += we * aw;
            }
        }
        int rem = n & 3;
        if ((int)threadIdx.x < rem) {
            int idx = lo + (nq << 2) + threadIdx.x;
            unsigned p = pairs[idx];
            float we = u2f(wp[idx]);
            ushort4 ua = sbf[p & 524287u];
            ushort4 ub = sbf[(B << BSH) + (int)(p >> 19)];
            float ax = u2f(ua.x), ay = u2f(ua.y), az = u2f(ua.z), aw = u2f(ua.w);
            float bx = u2f(ub.x), by = u2f(ub.y), bz = u2f(ub.z), bw = u2f(ub.w);
            acc[0] += we;
            acc[1] += we * (ax * bx + ay * by + az * bz + aw * bw);
            acc[2] += we * ax; acc[3] += we * ay;
            acc[4] += we * az; acc[5] += we * aw;
        }
    }
    __shared__ float part[8][6];
    int lane = threadIdx.x & 63, wid = threadIdx.x >> 6;
#pragma unroll
    for (int k = 0; k < 6; k++) {
        float r = waveReduceF(acc[k]);
        if (lane == 0) part[wid][k] = r;
    }
    __syncthreads();
    if (threadIdx.x < 6) {
        float vsum = 0.f;
#pragma unroll
        for (int wdi = 0; wdi < 8; wdi++) vsum += part[wdi][threadIdx.x];
        int off = (threadIdx.x == 0) ? 128 : (threadIdx.x == 1 ? 129 : 130 + threadIdx.x);
        atomicAdd(&scal[off], vsum);
    }
}

// ---------------- q ------------------------------------------------------------
__global__ void qk(const float* __restrict__ scal, float* __restrict__ out)
{
    if (threadIdx.x == 0) {
        float inv = 1.f / scal[128];
        float posv = scal[129] * inv;
        float acc = 0.f;
#pragma unroll
        for (int k = 0; k < 4; k++) {
            float d = scal[132 + k] * inv;
            acc += d * d;
        }
        out[(size_t)NN * 4] = posv - acc;
    }
}

extern "C" void kernel_launch(void* const* d_in, const int* in_sizes, int n_in,
                              void* d_out, int out_size, void* d_ws, size_t ws_size,
                              hipStream_t stream) {
    const float* x  = (const float*)d_in[0];
    const int*  ei  = (const int*)d_in[1];
    const int*  src = ei;
    const int*  dst = ei + NE;
    const float* w   = (const float*)d_in[2];
    const float* W1a = (const float*)d_in[3];  const float* b1a = (const float*)d_in[4];
    const float* W1b = (const float*)d_in[5];  const float* b1b = (const float*)d_in[6];
    const float* g1  = (const float*)d_in[7];  const float* be1 = (const float*)d_in[8];
    const float* W2a = (const float*)d_in[9];  const float* b2a = (const float*)d_in[10];
    const float* W2b = (const float*)d_in[11]; const float* b2b = (const float*)d_in[12];
    const float* g2  = (const float*)d_in[13]; const float* be2 = (const float*)d_in[14];
    const float* W3a = (const float*)d_in[15]; const float* b3a = (const float*)d_in[16];
    const float* W3b = (const float*)d_in[17]; const float* b3b = (const float*)d_in[18];
    const float* g3  = (const float*)d_in[19]; const float* be3 = (const float*)d_in[20];
    const float* Wf  = (const float*)d_in[21]; const float* bfb = (const float*)d_in[22];

    // workspace layout:
    //  floats sc[0..1023]: two_m@128, pos@129, ds@132..135, L@160..183,
    //    dm (20 doubles) @ float-idx 384 (byte 1536), cur ints @ sci[832]
    //  byte 4096: pairs uint[NB*CAP] (34.3MB) | wp ushort[NB*CAP] (17.1MB) |
    //    slab float[NAGG*2*BSZ] (32.25MB) | UN2 float2[NN] | SUN float2[NN] |
    //    SSU float[NN] | sbf ushort4[NN]
    float*  sc   = (float*)d_ws;
    int*    sci  = (int*)d_ws;
    double* dm   = (double*)(sc + 384);
    unsigned* pairs = (unsigned*)(sc + 1024);
    unsigned short* wp = (unsigned short*)(pairs + (size_t)NB * CAP);
    float*  slab = (float*)(wp + (size_t)NB * CAP);
    float2* UN2  = (float2*)(slab + (size_t)NAGG * 2 * BSZ);
    float2* SUN  = UN2 + NN;
    float*  SSU  = (float*)(SUN + NN);
    ushort4* sbf = (ushort4*)(SSU + NN);
    float*  sout = (float*)d_out;

    const int NB_N  = (NN + 255) / 256;
    const int NB_EQ = (NE / 4 + 1023) / 1024;   // 1954 blocks over int4-quads

    hipMemsetAsync(sc, 0, 4096, stream);
    initk<<<1, 128, 0, stream>>>(sci + 832);

    // bucketize once (dst -> 123 fixed-capacity buckets), block counting sort
    scatterk<<<NB_EQ, 512, 0, stream>>>((const int4*)src, (const int4*)dst,
                                        (const float4*)w, sci + 832, pairs, wp);

    // three aggregation rounds via LDS privatization, 4-wide gather ILP
    agg1k<<<NAGG, 512, 32768, stream>>>(pairs, sci + 832, x, slab);
    mergeN1<<<NB_N, 256, 0, stream>>>(slab, x, UN2);
    agg2k<<<NAGG, 512, 32768, stream>>>(pairs, sci + 832, UN2, slab);
    mergeN2<<<NB_N, 256, 0, stream>>>(slab, SUN);
    agg3k<<<NAGG, 512, 16384, stream>>>(pairs, sci + 832, SUN, slab);
    m3mom<<<NB_N, 256, 0, stream>>>(slab, UN2, SUN, SSU, dm);

    // closed-form logit matrix -> softmax -> modularity
    constk<<<1, 64, 0, stream>>>(W1a, b1a, W1b, b1b, g1, be1,
                                 W2a, b2a, W2b, b2b, g2, be2,
                                 W3a, b3a, W3b, b3b, g3, be3,
                                 Wf, bfb, dm, sc + 160);
    finalk<<<NB_N, 256, 0, stream>>>(UN2, SUN, SSU, sc + 160, (float4*)sout, sbf);
    modk<<<NAGG, 512, 0, stream>>>(pairs, wp, sci + 832, sbf, sc);
    qk<<<1, 64, 0, stream>>>(sc, sout);
}